// Round 9
// baseline (2407.328 us; speedup 1.0000x reference)
//
#include <hip/hip_runtime.h>

#define HH 128
#define WW 128
#define HWX (HH*WW)

using f32x4 = __attribute__((ext_vector_type(4))) float;
using f16x8 = __attribute__((ext_vector_type(8))) _Float16;

__device__ __forceinline__ unsigned short f16bits(_Float16 h) {
  union { _Float16 f; unsigned short u; } v; v.f = h; return v.u;
}

// chunk swizzle: position pos (64B row of 32 f16), chunk q (16B of 8 f16)
__device__ __forceinline__ int swz(int pos, int q) {
  return pos * 32 + (((q + pos + (pos >> 2)) & 3) << 3);
}

// ---------------------------------------------------------------------------
// Weight prep: OIHW fp32 -> [layer][kpos][O][I] split-fp16 (hi + lo arenas)
// ---------------------------------------------------------------------------
__global__ __launch_bounds__(256) void wprep_k(
    const float* __restrict__ src, unsigned short* __restrict__ dhi,
    unsigned short* __restrict__ dlo, int O, int I, int L)
{
  int idx = blockIdx.x * 256 + threadIdx.x;
  int tot = L * O * I * 9;
  if (idx >= tot) return;
  int per = O * I * 9;
  int layer = idx / per;
  int r = idx - layer * per;
  int o = r / (I * 9);
  int r2 = r - o * (I * 9);
  int i = r2 / 9, k = r2 - i * 9;
  float v = src[idx];
  _Float16 h = (_Float16)v;
  _Float16 l = (_Float16)(v - (float)h);
  long di = (long)layer * per + ((long)k * O + o) * I + i;
  dhi[di] = f16bits(h);
  dlo[di] = f16bits(l);
}

// ---------------------------------------------------------------------------
// Deform weight prep: [L][O=64][I=64][9] fp32 -> [L][k2][o][r=I] split-fp16
// ---------------------------------------------------------------------------
__global__ __launch_bounds__(256) void dwprep_k(
    const float* __restrict__ src, unsigned short* __restrict__ dhi,
    unsigned short* __restrict__ dlo)
{
  int idx = blockIdx.x * 256 + threadIdx.x;      // 4*36864 = 147456
  if (idx >= 147456) return;
  int l = idx / 36864;
  int rem = idx - l * 36864;
  int o = rem / 576;
  int rem2 = rem - o * 576;
  int r = rem2 / 9, k2 = rem2 - r * 9;
  float v = src[idx];
  _Float16 h = (_Float16)v;
  _Float16 lo = (_Float16)(v - (float)h);
  long di = (((long)l * 9 + k2) * 64 + o) * 64 + r;
  dhi[di] = f16bits(h);
  dlo[di] = f16bits(lo);
}

// ---------------------------------------------------------------------------
// Split-fp16 MFMA implicit-GEMM 3x3 SAME conv. Block 256 thr = 4 waves.
// v12: NO weight LDS. Each lane loads its B-fragment (16B hi + 16B lo)
// directly from global (L2-resident, shared by all blocks). Removes s_w,
// T14, and ALL per-kp barriers (36/block in R7-R8: each was a full
// vmcnt(0)+lgkmcnt(0) drain stalling every wave). Only s_in barriers remain
// (2 per cb). Waves fully decoupled through the kp loop; compiler free to
// hoist kp+1 weight loads under kp MFMAs. Extra L2 traffic ~370MB/dispatch
// @34.5TB/s ~= 11us — cheap vs removing the drain chain.
// Ledger: occupancy neutral (R7), staging VALU small win (R8, SIN/SOUT kept).
// ---------------------------------------------------------------------------
template<int CBLK, int NFRAG, bool RELU, bool ADD, bool CRMODE, bool SIN, int SOUT>
__global__ __launch_bounds__(256, 3) void conv_mfma_k(
    const float* __restrict__ in, const unsigned short* __restrict__ inlo,
    const unsigned short* __restrict__ whi, const unsigned short* __restrict__ wlo,
    const float* __restrict__ bias, const float* __restrict__ res,
    float* __restrict__ out, unsigned short* __restrict__ outh,
    unsigned short* __restrict__ outl,
    int Cout, int nslice, int img_in0, int img_out0)
{
  constexpr int CIN = CBLK * 32;
  constexpr int OCB = NFRAG * 16;
  __shared__ __align__(16) unsigned short s_in[2 * 10880];   // 10x34 halo hi|lo

  const int tid = threadIdx.x;
  const int lane = tid & 63;
  const int wv = tid >> 6;
  const int m16 = lane & 15, q = lane >> 4;
  const int iz = blockIdx.z / nslice, slice = blockIdx.z % nslice;
  const int oc_blk0 = slice * OCB;
  const int x0 = blockIdx.x * 32, y0 = blockIdx.y * 8;

  f32x4 acc[4][NFRAG];
#pragma unroll
  for (int mt = 0; mt < 4; ++mt)
#pragma unroll
    for (int nt = 0; nt < NFRAG; ++nt)
#pragma unroll
      for (int i = 0; i < 4; ++i) acc[mt][nt][i] = 0.f;

  int bb = 0, nn = 0;
  const float* inb = in;
  const unsigned short* inb_h = (const unsigned short*)in;
  const unsigned short* inb_l = inlo;
  if (CRMODE) {
    int j = img_in0 + iz;
    bb = j >> 2;
    int ns = j & 3;
    nn = ns < 2 ? ns : ns + 1;
  } else {
    if (SIN) {
      inb_h += (long)(img_in0 + iz) * CIN * HWX;
      inb_l += (long)(img_in0 + iz) * CIN * HWX;
    } else {
      inb = in + (long)(img_in0 + iz) * CIN * HWX;
    }
  }

  for (int cb = 0; cb < CBLK; ++cb) {
    const int c0 = cb * 32;
    if (cb > 0) __syncthreads();   // protect s_in overwrite from prev cb reads
    // ---- stage input tile ----
    for (int t = tid; t < 1360; t += 256) {
      int qq = t / 340, pos = t - qq * 340;
      int iy = pos / 34, ix = pos - iy * 34;
      int gy = y0 + iy - 1, gx = x0 + ix - 1;
      bool inr = (gy >= 0 && gy < HH && gx >= 0 && gx < WW);
      if (SIN) {
        uint4 hv = make_uint4(0u, 0u, 0u, 0u), lv = make_uint4(0u, 0u, 0u, 0u);
        if (inr) {
          long a;
          if (CRMODE) {
            int ch = c0 + qq * 8;
            int simg = (ch < 64) ? (bb * 5 + 2) : (bb * 5 + nn);
            a = ((long)(simg * 8 + ((ch & 63) >> 3)) * HWX + gy * WW + gx) * 8;
            hv = *(const uint4*)((const unsigned short*)in + a);
            lv = *(const uint4*)(inlo + a);
          } else {
            a = (long)(c0 + qq * 8) * HWX + (long)(gy * WW + gx) * 8;
            hv = *(const uint4*)(inb_h + a);
            lv = *(const uint4*)(inb_l + a);
          }
        }
        *(uint4*)(s_in + swz(pos, qq)) = hv;
        *(uint4*)(s_in + 10880 + swz(pos, qq)) = lv;
      } else {
        const float* src;
        if (CRMODE) {
          int ch = c0 + qq * 8;
          int simg = (ch < 64) ? (bb * 5 + 2) : (bb * 5 + nn);
          src = in + ((long)simg * 64 + (ch & 63)) * HWX + gy * WW + gx;
        } else {
          src = inb + (long)(c0 + qq * 8) * HWX + gy * WW + gx;
        }
        unsigned hi4[4], lo4[4];
#pragma unroll
        for (int j2 = 0; j2 < 4; ++j2) {
          unsigned short hs[2], ls[2];
#pragma unroll
          for (int j = 0; j < 2; ++j) {
            float v = inr ? src[(long)(j2 * 2 + j) * HWX] : 0.f;
            _Float16 h = (_Float16)v;
            _Float16 l = (_Float16)(v - (float)h);
            hs[j] = f16bits(h); ls[j] = f16bits(l);
          }
          hi4[j2] = (unsigned)hs[0] | ((unsigned)hs[1] << 16);
          lo4[j2] = (unsigned)ls[0] | ((unsigned)ls[1] << 16);
        }
        *(uint4*)(s_in + swz(pos, qq)) = make_uint4(hi4[0], hi4[1], hi4[2], hi4[3]);
        *(uint4*)(s_in + 10880 + swz(pos, qq)) =
            make_uint4(lo4[0], lo4[1], lo4[2], lo4[3]);
      }
    }
    __syncthreads();

#pragma unroll
    for (int kp = 0; kp < 9; ++kp) {
      const int dy = kp / 3, dx = kp - dy * 3;
      // B-fragments straight from global (L2-hit; no LDS, no barrier).
      f16x8 bhi[NFRAG], blo[NFRAG];
#pragma unroll
      for (int nt = 0; nt < NFRAG; ++nt) {
        long wo = ((long)kp * Cout + oc_blk0 + nt * 16 + m16) * CIN + c0 + q * 8;
        bhi[nt] = *(const f16x8*)(whi + wo);
        blo[nt] = *(const f16x8*)(wlo + wo);
      }
#pragma unroll
      for (int mt = 0; mt < 4; ++mt) {
        int r = 2 * wv + (mt >> 1), h = mt & 1;
        int pos = (r + dy) * 34 + h * 16 + m16 + dx;
        f16x8 ahi = *(const f16x8*)(s_in + swz(pos, q));
        f16x8 alo = *(const f16x8*)(s_in + 10880 + swz(pos, q));
#pragma unroll
        for (int nt = 0; nt < NFRAG; ++nt) {
          acc[mt][nt] = __builtin_amdgcn_mfma_f32_16x16x32_f16(
              ahi, blo[nt], acc[mt][nt], 0, 0, 0);
          acc[mt][nt] = __builtin_amdgcn_mfma_f32_16x16x32_f16(
              alo, bhi[nt], acc[mt][nt], 0, 0, 0);
          acc[mt][nt] = __builtin_amdgcn_mfma_f32_16x16x32_f16(
              ahi, bhi[nt], acc[mt][nt], 0, 0, 0);
        }
      }
    }
  }

  const int img_o = img_out0 + iz;
#pragma unroll
  for (int mt = 0; mt < 4; ++mt) {
    int r = 2 * wv + (mt >> 1), h = mt & 1;
    int y = y0 + r;
    int xb = x0 + h * 16 + q * 4;
#pragma unroll
    for (int nt = 0; nt < NFRAG; ++nt) {
      int oc = oc_blk0 + nt * 16 + m16;
      if (oc < Cout) {
        float bsv = bias[oc];
        long base = ((long)img_o * Cout + oc) * HWX + (long)y * WW + xb;
        long gbase = 0;
        if (SOUT)
          gbase = (long)img_o * Cout * HWX + (long)(oc >> 3) * HWX * 8 +
                  ((long)y * WW + xb) * 8 + (oc & 7);
#pragma unroll
        for (int i = 0; i < 4; ++i) {
          float v = acc[mt][nt][i] + bsv;
          if (RELU) v = fmaxf(v, 0.f);
          if (ADD) v += res[base + i];
          if (SOUT) {
            _Float16 hh = (_Float16)v;
            outh[gbase + (long)i * 8] = f16bits(hh);
            outl[gbase + (long)i * 8] = f16bits((_Float16)(v - (float)hh));
          }
          if (SOUT != 1) out[base + i] = v;
        }
      }
    }
  }
}

// ---------------------------------------------------------------------------
// Fallback VALU conv (conv_first CIN=3 and recon Cout=3).
// SOUT=2: dual-write fp32 + split grouped copy (for conv_first -> A).
// ---------------------------------------------------------------------------
template<int CIN, int CK, int OCB, bool RELU, bool ADD, int SOUT>
__global__ __launch_bounds__(256) void conv3x3_k(
    const float* __restrict__ in, const float* __restrict__ wgt,
    const float* __restrict__ bias, const float* __restrict__ res,
    float* __restrict__ out, unsigned short* __restrict__ outh,
    unsigned short* __restrict__ outl,
    int Cout, int nslice, int img_in0, int img_out0)
{
  __shared__ __align__(16) float s_in[CK][34][34];
  __shared__ __align__(16) float s_w[CK * 9 * OCB];

  const int tid = threadIdx.x;
  const int tx = tid & 31;
  const int ty = tid >> 5;
  const int iz = blockIdx.z / nslice;
  const int slice = blockIdx.z % nslice;
  const int oc0 = slice * OCB;
  const int x0 = blockIdx.x * 32;
  const int y0 = blockIdx.y * 32;

  float acc[4][OCB];
#pragma unroll
  for (int r = 0; r < 4; ++r)
#pragma unroll
    for (int o = 0; o < OCB; ++o) acc[r][o] = 0.f;

  const float* inb = in + (long)(img_in0 + iz) * CIN * HWX;

  for (int c0 = 0; c0 < CIN; c0 += CK) {
    __syncthreads();
    for (int idx = tid; idx < CK * 34 * 34; idx += 256) {
      int c = idx / 1156;
      int rem = idx % 1156;
      int iy = rem / 34, ix = rem % 34;
      int gy = y0 + iy - 1, gx = x0 + ix - 1;
      float v = 0.f;
      if (gy >= 0 && gy < HH && gx >= 0 && gx < WW)
        v = inb[(long)(c0 + c) * HWX + gy * WW + gx];
      s_in[c][iy][ix] = v;
    }
    for (int idx = tid; idx < CK * 9 * OCB; idx += 256) {
      int oc = idx % OCB;
      int ck = idx / OCB;
      int c = ck / 9, k = ck % 9;
      int ocg = oc0 + oc;
      float v = 0.f;
      if (ocg < Cout) v = wgt[((long)ocg * CIN + c0 + c) * 9 + k];
      s_w[idx] = v;
    }
    __syncthreads();

    for (int c = 0; c < CK; ++c) {
#pragma unroll
      for (int k = 0; k < 9; ++k) {
        const int ky = k / 3, kx = k % 3;
        float v0 = s_in[c][ty + ky][tx + kx];
        float v1 = s_in[c][ty + 8 + ky][tx + kx];
        float v2 = s_in[c][ty + 16 + ky][tx + kx];
        float v3 = s_in[c][ty + 24 + ky][tx + kx];
        const float4* wp = (const float4*)&s_w[(c * 9 + k) * OCB];
#pragma unroll
        for (int o4 = 0; o4 < OCB / 4; ++o4) {
          float4 w4 = wp[o4];
          acc[0][o4 * 4 + 0] += v0 * w4.x; acc[0][o4 * 4 + 1] += v0 * w4.y;
          acc[0][o4 * 4 + 2] += v0 * w4.z; acc[0][o4 * 4 + 3] += v0 * w4.w;
          acc[1][o4 * 4 + 0] += v1 * w4.x; acc[1][o4 * 4 + 1] += v1 * w4.y;
          acc[1][o4 * 4 + 2] += v1 * w4.z; acc[1][o4 * 4 + 3] += v1 * w4.w;
          acc[2][o4 * 4 + 0] += v2 * w4.x; acc[2][o4 * 4 + 1] += v2 * w4.y;
          acc[2][o4 * 4 + 2] += v2 * w4.z; acc[2][o4 * 4 + 3] += v2 * w4.w;
          acc[3][o4 * 4 + 0] += v3 * w4.x; acc[3][o4 * 4 + 1] += v3 * w4.y;
          acc[3][o4 * 4 + 2] += v3 * w4.z; acc[3][o4 * 4 + 3] += v3 * w4.w;
        }
      }
    }
  }

#pragma unroll
  for (int o = 0; o < OCB; ++o) {
    int ocg = oc0 + o;
    if (ocg < Cout) {
      float b = bias ? bias[ocg] : 0.f;
      long base = ((long)(img_out0 + iz) * Cout + ocg) * HWX;
#pragma unroll
      for (int r = 0; r < 4; ++r) {
        int y = y0 + ty + 8 * r;
        float v = acc[r][o] + b;
        if (RELU) v = fmaxf(v, 0.f);
        long ia = base + (long)y * WW + x0 + tx;
        if (ADD) v += res[ia];
        if (SOUT) {
          long ga = (long)(img_out0 + iz) * Cout * HWX + (long)(ocg >> 3) * HWX * 8 +
                    ((long)y * WW + x0 + tx) * 8 + (ocg & 7);
          _Float16 hh = (_Float16)v;
          outh[ga] = f16bits(hh);
          outl[ga] = f16bits((_Float16)(v - (float)hh));
        }
        out[ia] = v;
      }
    }
  }
}

// ---------------------------------------------------------------------------
__global__ __launch_bounds__(256) void regroup_k(
    const float* __restrict__ src, float* __restrict__ dst, int supp_mode)
{
  int idx = blockIdx.x * 256 + threadIdx.x;
  int c = idx & 7;
  int p = (idx >> 3) & 16383;
  int g = (idx >> 17) & 7;
  int img = idx >> 20;
  int simg = img;
  if (supp_mode) {
    int b = img >> 2, ns = img & 3;
    simg = b * 5 + (ns < 2 ? ns : ns + 1);
  }
  dst[idx] = src[((simg * 64 + g * 8 + c) * HWX) + p];
}

// ---------------------------------------------------------------------------
// Deform v3 (known-good, 155us). R1-R6 falsified every lever: waves (R1/R2),
// pipeline depth (R3), f16 bytes (R4 precision), split-f16 layout (R6 —
// regressed; equal total bytes). Surviving model: per-CU TA processes ~1
// lane-address/cy; fp32 gather floor = 75.6M addrs = ~123us. At 155us this
// config is ~78% of the precision-constrained floor. Frozen.
// ---------------------------------------------------------------------------
__global__ __launch_bounds__(256) void deform_mfma_k(
    const float* __restrict__ srcg, const float* __restrict__ off,
    const unsigned short* __restrict__ wh, const unsigned short* __restrict__ wl,
    float* __restrict__ out, int img0, int cmask, int cshift)
{
  __shared__ __align__(16) unsigned short s_w[2][2 * 4096];
  const int tid = threadIdx.x;
  const int lane = tid & 63;
  const int wv = tid >> 6;
  const int m16 = lane & 15, q = lane >> 4;
  const int bid = blockIdx.x;
  const int iz = bid & cmask;
  const int tile = bid >> cshift;
  const int img = img0 + iz;
  const int tp0 = tile * 64;
  const int p = tp0 + wv * 16 + m16;
  const float fy = (float)(p >> 7), fx = (float)(p & 127);
  const int rot = 8 * (m16 & 7);

  const float* offb = off + (long)iz * 144 * HWX + p;
  const float* sgq[2];
  sgq[0] = srcg + (long)(img * 8 + q) * HWX * 8;        // s=0: g=q
  sgq[1] = srcg + (long)(img * 8 + 4 + q) * HWX * 8;    // s=1: g=4+q

  float dyr[3], dxr[3];
  float pyr[2], pxr[2];
  float4 cr[2][8];

#define LOAD_OFF(T, SLOT) { \
    const float* ob_ = offb + ((long)(4 * ((T) & 1) + q) * 18 + 2 * ((T) >> 1)) * HWX; \
    dyr[SLOT] = ob_[0]; dxr[SLOT] = ob_[HWX]; }

#define ISSUE(T, SLOT, OS) { \
    const int k2_ = (T) >> 1; \
    float py_ = dyr[OS] + fy + (float)(k2_ / 3 - 1); \
    float px_ = dxr[OS] + fx + (float)(k2_ % 3 - 1); \
    pyr[SLOT] = py_; pxr[SLOT] = px_; \
    float y0f_ = floorf(py_), x0f_ = floorf(px_); \
    int yi0_ = (int)fminf(fmaxf(y0f_, 0.f), 127.f); \
    int yi1_ = (int)fminf(fmaxf(y0f_ + 1.f, 0.f), 127.f); \
    int xi0_ = (int)fminf(fmaxf(x0f_, 0.f), 127.f); \
    int xi1_ = (int)fminf(fmaxf(x0f_ + 1.f, 0.f), 127.f); \
    const float* sg_ = sgq[(T) & 1]; \
    const float4* p00_ = (const float4*)(sg_ + ((long)yi0_ * WW + xi0_) * 8); \
    const float4* p01_ = (const float4*)(sg_ + ((long)yi0_ * WW + xi1_) * 8); \
    const float4* p10_ = (const float4*)(sg_ + ((long)yi1_ * WW + xi0_) * 8); \
    const float4* p11_ = (const float4*)(sg_ + ((long)yi1_ * WW + xi1_) * 8); \
    cr[SLOT][0] = p00_[0]; cr[SLOT][1] = p00_[1]; \
    cr[SLOT][2] = p01_[0]; cr[SLOT][3] = p01_[1]; \
    cr[SLOT][4] = p10_[0]; cr[SLOT][5] = p10_[1]; \
    cr[SLOT][6] = p11_[0]; cr[SLOT][7] = p11_[1]; }

#define STAGE(K2) { \
    const int buf_ = (K2) & 1; \
    for (int t2 = tid; t2 < 512; t2 += 256) { \
      int o_ = t2 >> 3, j_ = t2 & 7; \
      int d_ = o_ * 64 + ((8 * j_ + 8 * (o_ & 7)) & 63); \
      long so_ = ((long)(K2) * 64 + o_) * 64 + 8 * j_; \
      *(uint4*)(s_w[buf_] + d_) = *(const uint4*)(wh + so_); \
      *(uint4*)(s_w[buf_] + 4096 + d_) = *(const uint4*)(wl + so_); \
    } }

#define PROCESS(T, SLOT) { \
    float py_ = pyr[SLOT], px_ = pxr[SLOT]; \
    float y0f_ = floorf(py_), x0f_ = floorf(px_); \
    float wy_ = py_ - y0f_, wx_ = px_ - x0f_; \
    float my0 = (y0f_ >= 0.f && y0f_ <= 127.f) ? 1.f : 0.f; \
    float my1 = (y0f_ >= -1.f && y0f_ <= 126.f) ? 1.f : 0.f; \
    float mx0 = (x0f_ >= 0.f && x0f_ <= 127.f) ? 1.f : 0.f; \
    float mx1 = (x0f_ >= -1.f && x0f_ <= 126.f) ? 1.f : 0.f; \
    float w00 = (1.f - wy_) * (1.f - wx_) * my0 * mx0; \
    float w01 = (1.f - wy_) * wx_ * my0 * mx1; \
    float w10 = wy_ * (1.f - wx_) * my1 * mx0; \
    float w11 = wy_ * wx_ * my1 * mx1; \
    f16x8 ah, al; \
    _Pragma("unroll") \
    for (int j = 0; j < 4; ++j) { \
      float v0 = w00 * ((const float*)&cr[SLOT][0])[j] + w01 * ((const float*)&cr[SLOT][2])[j] \
               + w10 * ((const float*)&cr[SLOT][4])[j] + w11 * ((const float*)&cr[SLOT][6])[j]; \
      float v1 = w00 * ((const float*)&cr[SLOT][1])[j] + w01 * ((const float*)&cr[SLOT][3])[j] \
               + w10 * ((const float*)&cr[SLOT][5])[j] + w11 * ((const float*)&cr[SLOT][7])[j]; \
      _Float16 h0 = (_Float16)v0; ah[j] = h0; al[j] = (_Float16)(v0 - (float)h0); \
      _Float16 h1 = (_Float16)v1; ah[4 + j] = h1; al[4 + j] = (_Float16)(v1 - (float)h1); \
    } \
    const unsigned short* wb_ = s_w[((T) >> 1) & 1]; \
    const int roff_ = (32 * ((T) & 1) + 8 * q + rot) & 63; \
    _Pragma("unroll") \
    for (int nt = 0; nt < 4; ++nt) { \
      int o_ = nt * 16 + m16; \
      f16x8 bh = *(const f16x8*)(wb_ + o_ * 64 + roff_); \
      f16x8 bl = *(const f16x8*)(wb_ + 4096 + o_ * 64 + roff_); \
      acc[nt] = __builtin_amdgcn_mfma_f32_16x16x32_f16(ah, bl, acc[nt], 0, 0, 0); \
      acc[nt] = __builtin_amdgcn_mfma_f32_16x16x32_f16(al, bh, acc[nt], 0, 0, 0); \
      acc[nt] = __builtin_amdgcn_mfma_f32_16x16x32_f16(ah, bh, acc[nt], 0, 0, 0); \
    } }

  f32x4 acc[4];
#pragma unroll
  for (int nt = 0; nt < 4; ++nt)
#pragma unroll
    for (int i = 0; i < 4; ++i) acc[nt][i] = 0.f;

  // prologue: fill offset ring, issue corners for step 0, stage slab 0
  LOAD_OFF(0, 0);
  LOAD_OFF(1, 1);
  ISSUE(0, 0, 0);
  LOAD_OFF(2, 2);
  STAGE(0);
  __syncthreads();

#pragma unroll
  for (int k2 = 0; k2 < 9; ++k2) {
    if (k2 < 8) STAGE(k2 + 1);
#pragma unroll
    for (int s = 0; s < 2; ++s) {
      const int t = 2 * k2 + s;
      if (t < 17) ISSUE(t + 1, (t + 1) & 1, (t + 1) % 3);
      if (t < 15) LOAD_OFF(t + 3, (t + 3) % 3);
      PROCESS(t, t & 1);
    }
    __syncthreads();
  }

#undef LOAD_OFF
#undef ISSUE
#undef STAGE
#undef PROCESS

  const long pb = tp0 + wv * 16 + q * 4;
#pragma unroll
  for (int nt = 0; nt < 4; ++nt) {
    int oc = nt * 16 + m16;
    float4 v;
    v.x = acc[nt][0]; v.y = acc[nt][1]; v.z = acc[nt][2]; v.w = acc[nt][3];
    *(float4*)(out + ((long)img * 64 + oc) * HWX + pb) = v;
  }
}

__global__ __launch_bounds__(256) void assemble_k(
    const float* __restrict__ x, const float* __restrict__ im,
    const float* __restrict__ out0, const float* __restrict__ fea,
    float* __restrict__ out)
{
  int idx = blockIdx.x * 256 + threadIdx.x;
  if (idx < 491520) {
    int within = idx % 49152;
    int n = (idx / 49152) % 5;
    int b = idx / (49152 * 5);
    float v;
    if (n == 2) v = x[(b * 5 + 2) * 49152 + within];
    else {
      int j = b * 4 + (n < 2 ? n : n - 1);
      v = im[j * 49152 + within];
    }
    out[idx] = v;
  } else if (idx < 10977280) {
    int idx2 = idx - 491520;
    int within = idx2 % 1048576;
    int n = (idx2 / 1048576) % 5;
    int b = idx2 / (1048576 * 5);
    float v;
    if (n == 2) v = out0[(b * 5 + 2) * 1048576 + within];
    else {
      int j = b * 4 + (n < 2 ? n : n - 1);
      v = fea[j * 1048576 + within];
    }
    out[idx] = v;
  }
}

// ---------------------------------------------------------------------------
extern "C" void kernel_launch(void* const* d_in, const int* in_sizes, int n_in,
                              void* d_out, int out_size, void* d_ws, size_t ws_size,
                              hipStream_t stream) {
  const float* x   = (const float*)d_in[0];
  const float* cfw = (const float*)d_in[1];
  const float* cfb = (const float*)d_in[2];
  const float* rw1 = (const float*)d_in[3];
  const float* rb1 = (const float*)d_in[4];
  const float* rw2 = (const float*)d_in[5];
  const float* rb2 = (const float*)d_in[6];
  const float* crw = (const float*)d_in[7];
  const float* crb = (const float*)d_in[8];
  const float* ofw = (const float*)d_in[9];
  const float* ofb = (const float*)d_in[10];
  const float* dcw = (const float*)d_in[11];
  const float* rcw = (const float*)d_in[12];
  const float* rcb = (const float*)d_in[13];
  float* out = (float*)d_out;

  // conv weight arenas (hi|lo), then deform weight arenas (hi|lo)
  unsigned short* WH = (unsigned short*)d_ws;
  unsigned short* WL = WH + 774144;
  unsigned short* DH = WH + 1548288;
  unsigned short* DL = DH + 147456;
  const long W_res1 = 0, W_res2 = 184320, W_cr = 368640, W_off = 442368;

  float* A = (float*)d_ws + 921600;                  // (10,64,HW) fp32
  float* C = A + 10485760;                           // fea ping (8,64,HW)
  float* D = C + 8388608;                            // grouped / im
  float* F = D + 8388608;                            // fea3
  float* OFF = F + 8388608;                          // offsets (chunk,144,HW)
  float* im = D;

  // split-f16 grouped arenas:
  //  r-split (res1 out -> res2 in): lives in old r region (C + D-head),
  //    exact footprint of old fp32 r (10.49M floats). Dead before cr writes C.
  //  A-split (conv_first/res2 out -> res1/cr in): lives in F + OFF-head,
  //    dead after cr (before OFF's first write at layer0). 41.9MB <= F+OFF.
  unsigned short* Rh = (unsigned short*)C;
  unsigned short* Rl = Rh + 10485760;
  unsigned short* Ah = (unsigned short*)F;
  unsigned short* Al = Ah + 10485760;

  const size_t fixedF = 921600UL + 10485760UL + 3UL * 8388608UL;
  int chunk = 8;
  while (chunk > 1 && (fixedF + (size_t)chunk * 2359296UL) * sizeof(float) > ws_size)
    chunk >>= 1;
  int cshift = (chunk == 8) ? 3 : (chunk == 4) ? 2 : (chunk == 2) ? 1 : 0;

  dim3 blk(256);

  // weight prep
  wprep_k<<<720, blk, 0, stream>>>(rw1, WH + W_res1, WL + W_res1, 64, 64, 5);
  wprep_k<<<720, blk, 0, stream>>>(rw2, WH + W_res2, WL + W_res2, 64, 64, 5);
  wprep_k<<<288, blk, 0, stream>>>(crw, WH + W_cr, WL + W_cr, 64, 128, 1);
  wprep_k<<<1296, blk, 0, stream>>>(ofw, WH + W_off, WL + W_off, 144, 64, 4);
  dwprep_k<<<576, blk, 0, stream>>>(dcw, DH, DL);

  // conv_first + ReLU : x -> A fp32 + A-split   [VALU fp32, CIN=3]
  conv3x3_k<3, 3, 16, true, false, 2><<<dim3(4, 4, 40), blk, 0, stream>>>(
      x, cfw, cfb, nullptr, A, Ah, Al, 64, 4, 0, 0);

  // 5 residual blocks (split-fp16 MFMA; split-staged I/O; global weights)
  for (int i = 0; i < 5; ++i) {
    // res1: A-split -> r-split (split-only out; r has no other consumer)
    conv_mfma_k<2, 4, true, false, false, true, 1><<<dim3(4, 16, 10), blk, 0, stream>>>(
        (const float*)Ah, Al, WH + W_res1 + (long)i * 36864, WL + W_res1 + (long)i * 36864,
        rb1 + i * 64, nullptr, nullptr, Rh, Rl, 64, 1, 0, 0);
    // res2: r-split -> A fp32 (+res add) + A-split
    conv_mfma_k<2, 4, false, true, false, true, 2><<<dim3(4, 16, 10), blk, 0, stream>>>(
        (const float*)Rh, Rl, WH + W_res2 + (long)i * 36864, WL + W_res2 + (long)i * 36864,
        rb2 + i * 64, A, A, Ah, Al, 64, 1, 0, 0);
  }

  // cr conv, fused concat(ref,supp) from A-split: -> C (fea0, fp32)
  conv_mfma_k<4, 4, false, false, true, true, 0><<<dim3(4, 16, 8), blk, 0, stream>>>(
      (const float*)Ah, Al, WH + W_cr, WL + W_cr, crb, nullptr, C, nullptr, nullptr,
      64, 1, 0, 0);

  // offset conv (fp32-staged) + deform (frozen), chunked
  auto off_deform = [&](const float* fea_in, const float* grouped,
                        int layer, float* outp) {
    for (int i0 = 0; i0 < 8; i0 += chunk) {
      conv_mfma_k<2, 3, false, false, false, false, 0>
          <<<dim3(4, 16, chunk * 3), blk, 0, stream>>>(
              fea_in, nullptr, WH + W_off + (long)layer * 82944,
              WL + W_off + (long)layer * 82944, ofb + layer * 144,
              nullptr, OFF, nullptr, nullptr, 144, 3, i0, 0);
      deform_mfma_k<<<dim3(256 * chunk), blk, 0, stream>>>(
          grouped, OFF, DH + (long)layer * 36864, DL + (long)layer * 36864,
          outp, i0, chunk - 1, cshift);
    }
  };

  // layer 0: fea1 = deform(fea0, conv(fea0))        C -> C
  regroup_k<<<32768, blk, 0, stream>>>(C, D, 0);
  off_deform(C, D, 0, C);

  // layer 1: fea2 = deform(fea1, conv(fea1))        C -> C
  regroup_k<<<32768, blk, 0, stream>>>(C, D, 0);
  off_deform(C, D, 1, C);

  // layer 2: fea3 = deform(supp, conv(fea2))        (A supp, C) -> F
  regroup_k<<<32768, blk, 0, stream>>>(A, D, 1);
  off_deform(C, D, 2, F);

  // layer 3: aligned = deform(fea3, conv(fea3))     F -> C
  regroup_k<<<32768, blk, 0, stream>>>(F, D, 0);
  off_deform(F, D, 3, C);

  // recon conv: aligned -> im (8,3,HW)   [VALU fp32, Cout=3]
  conv3x3_k<64, 8, 4, false, false, 0><<<dim3(4, 4, 8), blk, 0, stream>>>(
      C, rcw, rcb, nullptr, im, nullptr, nullptr, 3, 1, 0, 0);

  // assemble outputs
  assemble_k<<<42880, blk, 0, stream>>>(x, im, A, F, out);
}

// Round 10
// 1699.680 us; speedup vs baseline: 1.4163x; 1.4163x over previous
//
#include <hip/hip_runtime.h>

#define HH 128
#define WW 128
#define HWX (HH*WW)

using f32x4 = __attribute__((ext_vector_type(4))) float;
using f16x8 = __attribute__((ext_vector_type(8))) _Float16;

__device__ __forceinline__ unsigned short f16bits(_Float16 h) {
  union { _Float16 f; unsigned short u; } v; v.f = h; return v.u;
}

// chunk swizzle: position pos (64B row of 32 f16), chunk q (16B of 8 f16)
__device__ __forceinline__ int swz(int pos, int q) {
  return pos * 32 + (((q + pos + (pos >> 2)) & 3) << 3);
}

// ---------------------------------------------------------------------------
// Weight prep: OIHW fp32 -> [layer][kpos][O][I] split-fp16 (hi + lo arenas)
// ---------------------------------------------------------------------------
__global__ __launch_bounds__(256) void wprep_k(
    const float* __restrict__ src, unsigned short* __restrict__ dhi,
    unsigned short* __restrict__ dlo, int O, int I, int L)
{
  int idx = blockIdx.x * 256 + threadIdx.x;
  int tot = L * O * I * 9;
  if (idx >= tot) return;
  int per = O * I * 9;
  int layer = idx / per;
  int r = idx - layer * per;
  int o = r / (I * 9);
  int r2 = r - o * (I * 9);
  int i = r2 / 9, k = r2 - i * 9;
  float v = src[idx];
  _Float16 h = (_Float16)v;
  _Float16 l = (_Float16)(v - (float)h);
  long di = (long)layer * per + ((long)k * O + o) * I + i;
  dhi[di] = f16bits(h);
  dlo[di] = f16bits(l);
}

// ---------------------------------------------------------------------------
// Deform weight prep: [L][O=64][I=64][9] fp32 -> [L][k2][o][r=I] split-fp16
// ---------------------------------------------------------------------------
__global__ __launch_bounds__(256) void dwprep_k(
    const float* __restrict__ src, unsigned short* __restrict__ dhi,
    unsigned short* __restrict__ dlo)
{
  int idx = blockIdx.x * 256 + threadIdx.x;      // 4*36864 = 147456
  if (idx >= 147456) return;
  int l = idx / 36864;
  int rem = idx - l * 36864;
  int o = rem / 576;
  int rem2 = rem - o * 576;
  int r = rem2 / 9, k2 = rem2 - r * 9;
  float v = src[idx];
  _Float16 h = (_Float16)v;
  _Float16 lo = (_Float16)(v - (float)h);
  long di = (((long)l * 9 + k2) * 64 + o) * 64 + r;
  dhi[di] = f16bits(h);
  dlo[di] = f16bits(lo);
}

// ---------------------------------------------------------------------------
// Split-fp16 MFMA implicit-GEMM 3x3 SAME conv. Block 256 thr = 4 waves.
// Structure = R8 (session best, 1772us): single-buffered weight slab in LDS
// + T14 (next slab prefetched to regs during MFMAs, written after a
// read-complete barrier). R9 falsified the no-LDS variant (-36%: per-kp L2
// load latency un-hidden); R7 falsified barrier-count as the cost.
// SIN staging modes: 0 = planar fp32 (8 scalar loads strided 64KB),
// 1 = pre-split hi/lo arenas (2 coalesced 16B loads, zero conversion VALU),
// 2 = grouped fp32 [img][g][HW][8] (2 coalesced float4 loads + conversion;
//     bit-identical staged values to mode 0 — used by offset convs whose
//     regroup_k output D already holds their input in this layout).
// SOUT: 1 = split-only out, 2 = dual fp32 + split.
// ---------------------------------------------------------------------------
template<int CBLK, int NFRAG, bool RELU, bool ADD, bool CRMODE, int SIN, int SOUT>
__global__ __launch_bounds__(256, 3) void conv_mfma_k(
    const float* __restrict__ in, const unsigned short* __restrict__ inlo,
    const unsigned short* __restrict__ whi, const unsigned short* __restrict__ wlo,
    const float* __restrict__ bias, const float* __restrict__ res,
    float* __restrict__ out, unsigned short* __restrict__ outh,
    unsigned short* __restrict__ outl,
    int Cout, int nslice, int img_in0, int img_out0)
{
  constexpr int CIN = CBLK * 32;
  constexpr int OCB = NFRAG * 16;
  constexpr int SLAB = OCB * 32;               // ushorts per half
  __shared__ __align__(16) unsigned short s_in[2 * 10880];   // 10x34 halo hi|lo
  __shared__ __align__(16) unsigned short s_w[2 * SLAB];     // single buf hi|lo

  const int tid = threadIdx.x;
  const int lane = tid & 63;
  const int wv = tid >> 6;
  const int m16 = lane & 15, q = lane >> 4;
  const int iz = blockIdx.z / nslice, slice = blockIdx.z % nslice;
  const int oc_blk0 = slice * OCB;
  const int x0 = blockIdx.x * 32, y0 = blockIdx.y * 8;

  f32x4 acc[4][NFRAG];
#pragma unroll
  for (int mt = 0; mt < 4; ++mt)
#pragma unroll
    for (int nt = 0; nt < NFRAG; ++nt)
#pragma unroll
      for (int i = 0; i < 4; ++i) acc[mt][nt][i] = 0.f;

  int bb = 0, nn = 0;
  const float* inb = in;
  const unsigned short* inb_h = (const unsigned short*)in;
  const unsigned short* inb_l = inlo;
  if (CRMODE) {
    int j = img_in0 + iz;
    bb = j >> 2;
    int ns = j & 3;
    nn = ns < 2 ? ns : ns + 1;
  } else {
    if (SIN == 1) {
      inb_h += (long)(img_in0 + iz) * CIN * HWX;
      inb_l += (long)(img_in0 + iz) * CIN * HWX;
    } else {
      inb = in + (long)(img_in0 + iz) * CIN * HWX;   // planar or grouped base
    }
  }

  for (int cb = 0; cb < CBLK; ++cb) {
    const int c0 = cb * 32;
    if (cb > 0) __syncthreads();   // protect s_in/s_w overwrite from prev cb
    // ---- stage input tile ----
    for (int t = tid; t < 1360; t += 256) {
      int qq = t / 340, pos = t - qq * 340;
      int iy = pos / 34, ix = pos - iy * 34;
      int gy = y0 + iy - 1, gx = x0 + ix - 1;
      bool inr = (gy >= 0 && gy < HH && gx >= 0 && gx < WW);
      if (SIN == 1) {
        uint4 hv = make_uint4(0u, 0u, 0u, 0u), lv = make_uint4(0u, 0u, 0u, 0u);
        if (inr) {
          long a;
          if (CRMODE) {
            int ch = c0 + qq * 8;
            int simg = (ch < 64) ? (bb * 5 + 2) : (bb * 5 + nn);
            a = ((long)(simg * 8 + ((ch & 63) >> 3)) * HWX + gy * WW + gx) * 8;
            hv = *(const uint4*)((const unsigned short*)in + a);
            lv = *(const uint4*)(inlo + a);
          } else {
            a = (long)(c0 + qq * 8) * HWX + (long)(gy * WW + gx) * 8;
            hv = *(const uint4*)(inb_h + a);
            lv = *(const uint4*)(inb_l + a);
          }
        }
        *(uint4*)(s_in + swz(pos, qq)) = hv;
        *(uint4*)(s_in + 10880 + swz(pos, qq)) = lv;
      } else {
        float vals[8];
        if (SIN == 2) {
          if (inr) {
            long a = (long)((c0 >> 3) + qq) * HWX * 8 + (long)(gy * WW + gx) * 8;
            float4 f0 = ((const float4*)(inb + a))[0];
            float4 f1 = ((const float4*)(inb + a))[1];
            vals[0] = f0.x; vals[1] = f0.y; vals[2] = f0.z; vals[3] = f0.w;
            vals[4] = f1.x; vals[5] = f1.y; vals[6] = f1.z; vals[7] = f1.w;
          } else {
#pragma unroll
            for (int j = 0; j < 8; ++j) vals[j] = 0.f;
          }
        } else {
          const float* src;
          if (CRMODE) {
            int ch = c0 + qq * 8;
            int simg = (ch < 64) ? (bb * 5 + 2) : (bb * 5 + nn);
            src = in + ((long)simg * 64 + (ch & 63)) * HWX + gy * WW + gx;
          } else {
            src = inb + (long)(c0 + qq * 8) * HWX + gy * WW + gx;
          }
#pragma unroll
          for (int j = 0; j < 8; ++j)
            vals[j] = inr ? src[(long)j * HWX] : 0.f;
        }
        unsigned hi4[4], lo4[4];
#pragma unroll
        for (int j2 = 0; j2 < 4; ++j2) {
          unsigned short hs[2], ls[2];
#pragma unroll
          for (int j = 0; j < 2; ++j) {
            float v = vals[j2 * 2 + j];
            _Float16 h = (_Float16)v;
            _Float16 l = (_Float16)(v - (float)h);
            hs[j] = f16bits(h); ls[j] = f16bits(l);
          }
          hi4[j2] = (unsigned)hs[0] | ((unsigned)hs[1] << 16);
          lo4[j2] = (unsigned)ls[0] | ((unsigned)ls[1] << 16);
        }
        *(uint4*)(s_in + swz(pos, qq)) = make_uint4(hi4[0], hi4[1], hi4[2], hi4[3]);
        *(uint4*)(s_in + 10880 + swz(pos, qq)) =
            make_uint4(lo4[0], lo4[1], lo4[2], lo4[3]);
      }
    }
    // ---- stage kp=0 weight slab ----
    for (int t = tid; t < OCB * 4; t += 256) {
      int qq = t & 3, ocl = t >> 2;
      long so = ((long)0 * Cout + oc_blk0 + ocl) * CIN + c0 + qq * 8;
      *(uint4*)(s_w + swz(ocl, qq)) = *(const uint4*)(whi + so);
      *(uint4*)(s_w + SLAB + swz(ocl, qq)) = *(const uint4*)(wlo + so);
    }
    __syncthreads();

#pragma unroll
    for (int kp = 0; kp < 9; ++kp) {
      // T14: issue next-slab global loads now (regs); write after read-barrier.
      uint4 sth, stl;
      int sd = -1;
      if (kp < 8 && tid < OCB * 4) {
        int qq = tid & 3, ocl = tid >> 2;
        long so = ((long)(kp + 1) * Cout + oc_blk0 + ocl) * CIN + c0 + qq * 8;
        sth = *(const uint4*)(whi + so);
        stl = *(const uint4*)(wlo + so);
        sd = swz(ocl, qq);
      }
      const int dy = kp / 3, dx = kp - dy * 3;
      f16x8 bhi[NFRAG], blo[NFRAG];
#pragma unroll
      for (int nt = 0; nt < NFRAG; ++nt) {
        int pw = nt * 16 + m16;
        bhi[nt] = *(const f16x8*)(s_w + swz(pw, q));
        blo[nt] = *(const f16x8*)(s_w + SLAB + swz(pw, q));
      }
#pragma unroll
      for (int mt = 0; mt < 4; ++mt) {
        int r = 2 * wv + (mt >> 1), h = mt & 1;
        int pos = (r + dy) * 34 + h * 16 + m16 + dx;
        f16x8 ahi = *(const f16x8*)(s_in + swz(pos, q));
        f16x8 alo = *(const f16x8*)(s_in + 10880 + swz(pos, q));
#pragma unroll
        for (int nt = 0; nt < NFRAG; ++nt) {
          acc[mt][nt] = __builtin_amdgcn_mfma_f32_16x16x32_f16(
              ahi, blo[nt], acc[mt][nt], 0, 0, 0);
          acc[mt][nt] = __builtin_amdgcn_mfma_f32_16x16x32_f16(
              alo, bhi[nt], acc[mt][nt], 0, 0, 0);
          acc[mt][nt] = __builtin_amdgcn_mfma_f32_16x16x32_f16(
              ahi, bhi[nt], acc[mt][nt], 0, 0, 0);
        }
      }
      if (kp < 8) {
        __syncthreads();           // all waves done reading s_w for this kp
        if (sd >= 0) {
          *(uint4*)(s_w + sd) = sth;
          *(uint4*)(s_w + SLAB + sd) = stl;
        }
        __syncthreads();           // slab ready for kp+1
      }
    }
  }

  const int img_o = img_out0 + iz;
#pragma unroll
  for (int mt = 0; mt < 4; ++mt) {
    int r = 2 * wv + (mt >> 1), h = mt & 1;
    int y = y0 + r;
    int xb = x0 + h * 16 + q * 4;
#pragma unroll
    for (int nt = 0; nt < NFRAG; ++nt) {
      int oc = oc_blk0 + nt * 16 + m16;
      if (oc < Cout) {
        float bsv = bias[oc];
        long base = ((long)img_o * Cout + oc) * HWX + (long)y * WW + xb;
        long gbase = 0;
        if (SOUT)
          gbase = (long)img_o * Cout * HWX + (long)(oc >> 3) * HWX * 8 +
                  ((long)y * WW + xb) * 8 + (oc & 7);
#pragma unroll
        for (int i = 0; i < 4; ++i) {
          float v = acc[mt][nt][i] + bsv;
          if (RELU) v = fmaxf(v, 0.f);
          if (ADD) v += res[base + i];
          if (SOUT) {
            _Float16 hh = (_Float16)v;
            outh[gbase + (long)i * 8] = f16bits(hh);
            outl[gbase + (long)i * 8] = f16bits((_Float16)(v - (float)hh));
          }
          if (SOUT != 1) out[base + i] = v;
        }
      }
    }
  }
}

// ---------------------------------------------------------------------------
// Fallback VALU conv (conv_first CIN=3 and recon Cout=3).
// SOUT=2: dual-write fp32 + split grouped copy (for conv_first -> A).
// ---------------------------------------------------------------------------
template<int CIN, int CK, int OCB, bool RELU, bool ADD, int SOUT>
__global__ __launch_bounds__(256) void conv3x3_k(
    const float* __restrict__ in, const float* __restrict__ wgt,
    const float* __restrict__ bias, const float* __restrict__ res,
    float* __restrict__ out, unsigned short* __restrict__ outh,
    unsigned short* __restrict__ outl,
    int Cout, int nslice, int img_in0, int img_out0)
{
  __shared__ __align__(16) float s_in[CK][34][34];
  __shared__ __align__(16) float s_w[CK * 9 * OCB];

  const int tid = threadIdx.x;
  const int tx = tid & 31;
  const int ty = tid >> 5;
  const int iz = blockIdx.z / nslice;
  const int slice = blockIdx.z % nslice;
  const int oc0 = slice * OCB;
  const int x0 = blockIdx.x * 32;
  const int y0 = blockIdx.y * 32;

  float acc[4][OCB];
#pragma unroll
  for (int r = 0; r < 4; ++r)
#pragma unroll
    for (int o = 0; o < OCB; ++o) acc[r][o] = 0.f;

  const float* inb = in + (long)(img_in0 + iz) * CIN * HWX;

  for (int c0 = 0; c0 < CIN; c0 += CK) {
    __syncthreads();
    for (int idx = tid; idx < CK * 34 * 34; idx += 256) {
      int c = idx / 1156;
      int rem = idx % 1156;
      int iy = rem / 34, ix = rem % 34;
      int gy = y0 + iy - 1, gx = x0 + ix - 1;
      float v = 0.f;
      if (gy >= 0 && gy < HH && gx >= 0 && gx < WW)
        v = inb[(long)(c0 + c) * HWX + gy * WW + gx];
      s_in[c][iy][ix] = v;
    }
    for (int idx = tid; idx < CK * 9 * OCB; idx += 256) {
      int oc = idx % OCB;
      int ck = idx / OCB;
      int c = ck / 9, k = ck % 9;
      int ocg = oc0 + oc;
      float v = 0.f;
      if (ocg < Cout) v = wgt[((long)ocg * CIN + c0 + c) * 9 + k];
      s_w[idx] = v;
    }
    __syncthreads();

    for (int c = 0; c < CK; ++c) {
#pragma unroll
      for (int k = 0; k < 9; ++k) {
        const int ky = k / 3, kx = k % 3;
        float v0 = s_in[c][ty + ky][tx + kx];
        float v1 = s_in[c][ty + 8 + ky][tx + kx];
        float v2 = s_in[c][ty + 16 + ky][tx + kx];
        float v3 = s_in[c][ty + 24 + ky][tx + kx];
        const float4* wp = (const float4*)&s_w[(c * 9 + k) * OCB];
#pragma unroll
        for (int o4 = 0; o4 < OCB / 4; ++o4) {
          float4 w4 = wp[o4];
          acc[0][o4 * 4 + 0] += v0 * w4.x; acc[0][o4 * 4 + 1] += v0 * w4.y;
          acc[0][o4 * 4 + 2] += v0 * w4.z; acc[0][o4 * 4 + 3] += v0 * w4.w;
          acc[1][o4 * 4 + 0] += v1 * w4.x; acc[1][o4 * 4 + 1] += v1 * w4.y;
          acc[1][o4 * 4 + 2] += v1 * w4.z; acc[1][o4 * 4 + 3] += v1 * w4.w;
          acc[2][o4 * 4 + 0] += v2 * w4.x; acc[2][o4 * 4 + 1] += v2 * w4.y;
          acc[2][o4 * 4 + 2] += v2 * w4.z; acc[2][o4 * 4 + 3] += v2 * w4.w;
          acc[3][o4 * 4 + 0] += v3 * w4.x; acc[3][o4 * 4 + 1] += v3 * w4.y;
          acc[3][o4 * 4 + 2] += v3 * w4.z; acc[3][o4 * 4 + 3] += v3 * w4.w;
        }
      }
    }
  }

#pragma unroll
  for (int o = 0; o < OCB; ++o) {
    int ocg = oc0 + o;
    if (ocg < Cout) {
      float b = bias ? bias[ocg] : 0.f;
      long base = ((long)(img_out0 + iz) * Cout + ocg) * HWX;
#pragma unroll
      for (int r = 0; r < 4; ++r) {
        int y = y0 + ty + 8 * r;
        float v = acc[r][o] + b;
        if (RELU) v = fmaxf(v, 0.f);
        long ia = base + (long)y * WW + x0 + tx;
        if (ADD) v += res[ia];
        if (SOUT) {
          long ga = (long)(img_out0 + iz) * Cout * HWX + (long)(ocg >> 3) * HWX * 8 +
                    ((long)y * WW + x0 + tx) * 8 + (ocg & 7);
          _Float16 hh = (_Float16)v;
          outh[ga] = f16bits(hh);
          outl[ga] = f16bits((_Float16)(v - (float)hh));
        }
        out[ia] = v;
      }
    }
  }
}

// ---------------------------------------------------------------------------
__global__ __launch_bounds__(256) void regroup_k(
    const float* __restrict__ src, float* __restrict__ dst, int supp_mode)
{
  int idx = blockIdx.x * 256 + threadIdx.x;
  int c = idx & 7;
  int p = (idx >> 3) & 16383;
  int g = (idx >> 17) & 7;
  int img = idx >> 20;
  int simg = img;
  if (supp_mode) {
    int b = img >> 2, ns = img & 3;
    simg = b * 5 + (ns < 2 ? ns : ns + 1);
  }
  dst[idx] = src[((simg * 64 + g * 8 + c) * HWX) + p];
}

// ---------------------------------------------------------------------------
// Deform v3 (known-good, 155us). R1-R6 falsified every lever: waves (R1/R2),
// pipeline depth (R3), f16 bytes (R4 precision), split-f16 layout (R6 —
// regressed; equal total bytes). Surviving model: per-CU TA processes ~1
// lane-address/cy; fp32 gather floor = 75.6M addrs = ~123us. At 155us this
// config is ~78% of the precision-constrained floor. Frozen.
// ---------------------------------------------------------------------------
__global__ __launch_bounds__(256) void deform_mfma_k(
    const float* __restrict__ srcg, const float* __restrict__ off,
    const unsigned short* __restrict__ wh, const unsigned short* __restrict__ wl,
    float* __restrict__ out, int img0, int cmask, int cshift)
{
  __shared__ __align__(16) unsigned short s_w[2][2 * 4096];
  const int tid = threadIdx.x;
  const int lane = tid & 63;
  const int wv = tid >> 6;
  const int m16 = lane & 15, q = lane >> 4;
  const int bid = blockIdx.x;
  const int iz = bid & cmask;
  const int tile = bid >> cshift;
  const int img = img0 + iz;
  const int tp0 = tile * 64;
  const int p = tp0 + wv * 16 + m16;
  const float fy = (float)(p >> 7), fx = (float)(p & 127);
  const int rot = 8 * (m16 & 7);

  const float* offb = off + (long)iz * 144 * HWX + p;
  const float* sgq[2];
  sgq[0] = srcg + (long)(img * 8 + q) * HWX * 8;        // s=0: g=q
  sgq[1] = srcg + (long)(img * 8 + 4 + q) * HWX * 8;    // s=1: g=4+q

  float dyr[3], dxr[3];
  float pyr[2], pxr[2];
  float4 cr[2][8];

#define LOAD_OFF(T, SLOT) { \
    const float* ob_ = offb + ((long)(4 * ((T) & 1) + q) * 18 + 2 * ((T) >> 1)) * HWX; \
    dyr[SLOT] = ob_[0]; dxr[SLOT] = ob_[HWX]; }

#define ISSUE(T, SLOT, OS) { \
    const int k2_ = (T) >> 1; \
    float py_ = dyr[OS] + fy + (float)(k2_ / 3 - 1); \
    float px_ = dxr[OS] + fx + (float)(k2_ % 3 - 1); \
    pyr[SLOT] = py_; pxr[SLOT] = px_; \
    float y0f_ = floorf(py_), x0f_ = floorf(px_); \
    int yi0_ = (int)fminf(fmaxf(y0f_, 0.f), 127.f); \
    int yi1_ = (int)fminf(fmaxf(y0f_ + 1.f, 0.f), 127.f); \
    int xi0_ = (int)fminf(fmaxf(x0f_, 0.f), 127.f); \
    int xi1_ = (int)fminf(fmaxf(x0f_ + 1.f, 0.f), 127.f); \
    const float* sg_ = sgq[(T) & 1]; \
    const float4* p00_ = (const float4*)(sg_ + ((long)yi0_ * WW + xi0_) * 8); \
    const float4* p01_ = (const float4*)(sg_ + ((long)yi0_ * WW + xi1_) * 8); \
    const float4* p10_ = (const float4*)(sg_ + ((long)yi1_ * WW + xi0_) * 8); \
    const float4* p11_ = (const float4*)(sg_ + ((long)yi1_ * WW + xi1_) * 8); \
    cr[SLOT][0] = p00_[0]; cr[SLOT][1] = p00_[1]; \
    cr[SLOT][2] = p01_[0]; cr[SLOT][3] = p01_[1]; \
    cr[SLOT][4] = p10_[0]; cr[SLOT][5] = p10_[1]; \
    cr[SLOT][6] = p11_[0]; cr[SLOT][7] = p11_[1]; }

#define STAGE(K2) { \
    const int buf_ = (K2) & 1; \
    for (int t2 = tid; t2 < 512; t2 += 256) { \
      int o_ = t2 >> 3, j_ = t2 & 7; \
      int d_ = o_ * 64 + ((8 * j_ + 8 * (o_ & 7)) & 63); \
      long so_ = ((long)(K2) * 64 + o_) * 64 + 8 * j_; \
      *(uint4*)(s_w[buf_] + d_) = *(const uint4*)(wh + so_); \
      *(uint4*)(s_w[buf_] + 4096 + d_) = *(const uint4*)(wl + so_); \
    } }

#define PROCESS(T, SLOT) { \
    float py_ = pyr[SLOT], px_ = pxr[SLOT]; \
    float y0f_ = floorf(py_), x0f_ = floorf(px_); \
    float wy_ = py_ - y0f_, wx_ = px_ - x0f_; \
    float my0 = (y0f_ >= 0.f && y0f_ <= 127.f) ? 1.f : 0.f; \
    float my1 = (y0f_ >= -1.f && y0f_ <= 126.f) ? 1.f : 0.f; \
    float mx0 = (x0f_ >= 0.f && x0f_ <= 127.f) ? 1.f : 0.f; \
    float mx1 = (x0f_ >= -1.f && x0f_ <= 126.f) ? 1.f : 0.f; \
    float w00 = (1.f - wy_) * (1.f - wx_) * my0 * mx0; \
    float w01 = (1.f - wy_) * wx_ * my0 * mx1; \
    float w10 = wy_ * (1.f - wx_) * my1 * mx0; \
    float w11 = wy_ * wx_ * my1 * mx1; \
    f16x8 ah, al; \
    _Pragma("unroll") \
    for (int j = 0; j < 4; ++j) { \
      float v0 = w00 * ((const float*)&cr[SLOT][0])[j] + w01 * ((const float*)&cr[SLOT][2])[j] \
               + w10 * ((const float*)&cr[SLOT][4])[j] + w11 * ((const float*)&cr[SLOT][6])[j]; \
      float v1 = w00 * ((const float*)&cr[SLOT][1])[j] + w01 * ((const float*)&cr[SLOT][3])[j] \
               + w10 * ((const float*)&cr[SLOT][5])[j] + w11 * ((const float*)&cr[SLOT][7])[j]; \
      _Float16 h0 = (_Float16)v0; ah[j] = h0; al[j] = (_Float16)(v0 - (float)h0); \
      _Float16 h1 = (_Float16)v1; ah[4 + j] = h1; al[4 + j] = (_Float16)(v1 - (float)h1); \
    } \
    const unsigned short* wb_ = s_w[((T) >> 1) & 1]; \
    const int roff_ = (32 * ((T) & 1) + 8 * q + rot) & 63; \
    _Pragma("unroll") \
    for (int nt = 0; nt < 4; ++nt) { \
      int o_ = nt * 16 + m16; \
      f16x8 bh = *(const f16x8*)(wb_ + o_ * 64 + roff_); \
      f16x8 bl = *(const f16x8*)(wb_ + 4096 + o_ * 64 + roff_); \
      acc[nt] = __builtin_amdgcn_mfma_f32_16x16x32_f16(ah, bl, acc[nt], 0, 0, 0); \
      acc[nt] = __builtin_amdgcn_mfma_f32_16x16x32_f16(al, bh, acc[nt], 0, 0, 0); \
      acc[nt] = __builtin_amdgcn_mfma_f32_16x16x32_f16(ah, bh, acc[nt], 0, 0, 0); \
    } }

  f32x4 acc[4];
#pragma unroll
  for (int nt = 0; nt < 4; ++nt)
#pragma unroll
    for (int i = 0; i < 4; ++i) acc[nt][i] = 0.f;

  // prologue: fill offset ring, issue corners for step 0, stage slab 0
  LOAD_OFF(0, 0);
  LOAD_OFF(1, 1);
  ISSUE(0, 0, 0);
  LOAD_OFF(2, 2);
  STAGE(0);
  __syncthreads();

#pragma unroll
  for (int k2 = 0; k2 < 9; ++k2) {
    if (k2 < 8) STAGE(k2 + 1);
#pragma unroll
    for (int s = 0; s < 2; ++s) {
      const int t = 2 * k2 + s;
      if (t < 17) ISSUE(t + 1, (t + 1) & 1, (t + 1) % 3);
      if (t < 15) LOAD_OFF(t + 3, (t + 3) % 3);
      PROCESS(t, t & 1);
    }
    __syncthreads();
  }

#undef LOAD_OFF
#undef ISSUE
#undef STAGE
#undef PROCESS

  const long pb = tp0 + wv * 16 + q * 4;
#pragma unroll
  for (int nt = 0; nt < 4; ++nt) {
    int oc = nt * 16 + m16;
    float4 v;
    v.x = acc[nt][0]; v.y = acc[nt][1]; v.z = acc[nt][2]; v.w = acc[nt][3];
    *(float4*)(out + ((long)img * 64 + oc) * HWX + pb) = v;
  }
}

__global__ __launch_bounds__(256) void assemble_k(
    const float* __restrict__ x, const float* __restrict__ im,
    const float* __restrict__ out0, const float* __restrict__ fea,
    float* __restrict__ out)
{
  int idx = blockIdx.x * 256 + threadIdx.x;
  if (idx < 491520) {
    int within = idx % 49152;
    int n = (idx / 49152) % 5;
    int b = idx / (49152 * 5);
    float v;
    if (n == 2) v = x[(b * 5 + 2) * 49152 + within];
    else {
      int j = b * 4 + (n < 2 ? n : n - 1);
      v = im[j * 49152 + within];
    }
    out[idx] = v;
  } else if (idx < 10977280) {
    int idx2 = idx - 491520;
    int within = idx2 % 1048576;
    int n = (idx2 / 1048576) % 5;
    int b = idx2 / (1048576 * 5);
    float v;
    if (n == 2) v = out0[(b * 5 + 2) * 1048576 + within];
    else {
      int j = b * 4 + (n < 2 ? n : n - 1);
      v = fea[j * 1048576 + within];
    }
    out[idx] = v;
  }
}

// ---------------------------------------------------------------------------
extern "C" void kernel_launch(void* const* d_in, const int* in_sizes, int n_in,
                              void* d_out, int out_size, void* d_ws, size_t ws_size,
                              hipStream_t stream) {
  const float* x   = (const float*)d_in[0];
  const float* cfw = (const float*)d_in[1];
  const float* cfb = (const float*)d_in[2];
  const float* rw1 = (const float*)d_in[3];
  const float* rb1 = (const float*)d_in[4];
  const float* rw2 = (const float*)d_in[5];
  const float* rb2 = (const float*)d_in[6];
  const float* crw = (const float*)d_in[7];
  const float* crb = (const float*)d_in[8];
  const float* ofw = (const float*)d_in[9];
  const float* ofb = (const float*)d_in[10];
  const float* dcw = (const float*)d_in[11];
  const float* rcw = (const float*)d_in[12];
  const float* rcb = (const float*)d_in[13];
  float* out = (float*)d_out;

  // conv weight arenas (hi|lo), then deform weight arenas (hi|lo)
  unsigned short* WH = (unsigned short*)d_ws;
  unsigned short* WL = WH + 774144;
  unsigned short* DH = WH + 1548288;
  unsigned short* DL = DH + 147456;
  const long W_res1 = 0, W_res2 = 184320, W_cr = 368640, W_off = 442368;

  float* A = (float*)d_ws + 921600;                  // (10,64,HW) fp32
  float* C = A + 10485760;                           // fea ping (8,64,HW)
  float* D = C + 8388608;                            // grouped / im
  float* F = D + 8388608;                            // fea3
  float* OFF = F + 8388608;                          // offsets (chunk,144,HW)
  float* im = D;

  // split-f16 grouped arenas:
  //  r-split (res1 out -> res2 in): lives in old r region (C + D-head),
  //    exact footprint of old fp32 r (10.49M floats). Dead before cr writes C.
  //  A-split (conv_first/res2 out -> res1/cr in): lives in F + OFF-head,
  //    dead after cr (before OFF's first write at layer0). 41.9MB <= F+OFF.
  unsigned short* Rh = (unsigned short*)C;
  unsigned short* Rl = Rh + 10485760;
  unsigned short* Ah = (unsigned short*)F;
  unsigned short* Al = Ah + 10485760;

  const size_t fixedF = 921600UL + 10485760UL + 3UL * 8388608UL;
  int chunk = 8;
  while (chunk > 1 && (fixedF + (size_t)chunk * 2359296UL) * sizeof(float) > ws_size)
    chunk >>= 1;
  int cshift = (chunk == 8) ? 3 : (chunk == 4) ? 2 : (chunk == 2) ? 1 : 0;

  dim3 blk(256);

  // weight prep
  wprep_k<<<720, blk, 0, stream>>>(rw1, WH + W_res1, WL + W_res1, 64, 64, 5);
  wprep_k<<<720, blk, 0, stream>>>(rw2, WH + W_res2, WL + W_res2, 64, 64, 5);
  wprep_k<<<288, blk, 0, stream>>>(crw, WH + W_cr, WL + W_cr, 64, 128, 1);
  wprep_k<<<1296, blk, 0, stream>>>(ofw, WH + W_off, WL + W_off, 144, 64, 4);
  dwprep_k<<<576, blk, 0, stream>>>(dcw, DH, DL);

  // conv_first + ReLU : x -> A fp32 + A-split   [VALU fp32, CIN=3]
  conv3x3_k<3, 3, 16, true, false, 2><<<dim3(4, 4, 40), blk, 0, stream>>>(
      x, cfw, cfb, nullptr, A, Ah, Al, 64, 4, 0, 0);

  // 5 residual blocks (split-fp16 MFMA; split-staged I/O; LDS weights + T14)
  for (int i = 0; i < 5; ++i) {
    // res1: A-split -> r-split (split-only out; r has no other consumer)
    conv_mfma_k<2, 4, true, false, false, 1, 1><<<dim3(4, 16, 10), blk, 0, stream>>>(
        (const float*)Ah, Al, WH + W_res1 + (long)i * 36864, WL + W_res1 + (long)i * 36864,
        rb1 + i * 64, nullptr, nullptr, Rh, Rl, 64, 1, 0, 0);
    // res2: r-split -> A fp32 (+res add) + A-split
    conv_mfma_k<2, 4, false, true, false, 1, 2><<<dim3(4, 16, 10), blk, 0, stream>>>(
        (const float*)Rh, Rl, WH + W_res2 + (long)i * 36864, WL + W_res2 + (long)i * 36864,
        rb2 + i * 64, A, A, Ah, Al, 64, 1, 0, 0);
  }

  // cr conv, fused concat(ref,supp) from A-split: -> C (fea0, fp32)
  conv_mfma_k<4, 4, false, false, true, 1, 0><<<dim3(4, 16, 8), blk, 0, stream>>>(
      (const float*)Ah, Al, WH + W_cr, WL + W_cr, crb, nullptr, C, nullptr, nullptr,
      64, 1, 0, 0);

  // offset conv + deform (frozen), chunked.
  // gin=true: stage offset-conv input from the grouped fp32 arena D (written
  // by regroup just before; bit-identical values, coalesced float4 loads)
  // instead of 8x 64KB-strided scalar loads from the planar fea.
  auto off_deform = [&](const float* fea_in, const float* grouped,
                        int layer, float* outp, bool gin) {
    for (int i0 = 0; i0 < 8; i0 += chunk) {
      if (gin)
        conv_mfma_k<2, 3, false, false, false, 2, 0>
            <<<dim3(4, 16, chunk * 3), blk, 0, stream>>>(
                grouped, nullptr, WH + W_off + (long)layer * 82944,
                WL + W_off + (long)layer * 82944, ofb + layer * 144,
                nullptr, OFF, nullptr, nullptr, 144, 3, i0, 0);
      else
        conv_mfma_k<2, 3, false, false, false, 0, 0>
            <<<dim3(4, 16, chunk * 3), blk, 0, stream>>>(
                fea_in, nullptr, WH + W_off + (long)layer * 82944,
                WL + W_off + (long)layer * 82944, ofb + layer * 144,
                nullptr, OFF, nullptr, nullptr, 144, 3, i0, 0);
      deform_mfma_k<<<dim3(256 * chunk), blk, 0, stream>>>(
          grouped, OFF, DH + (long)layer * 36864, DL + (long)layer * 36864,
          outp, i0, chunk - 1, cshift);
    }
  };

  // layer 0: fea1 = deform(fea0, conv(fea0))        C -> C   (D == grouped C)
  regroup_k<<<32768, blk, 0, stream>>>(C, D, 0);
  off_deform(C, D, 0, C, true);

  // layer 1: fea2 = deform(fea1, conv(fea1))        C -> C   (D == grouped C)
  regroup_k<<<32768, blk, 0, stream>>>(C, D, 0);
  off_deform(C, D, 1, C, true);

  // layer 2: fea3 = deform(supp, conv(fea2))        (A supp, C) -> F
  //          grouped D == supp-A, off-conv input is C -> planar path
  regroup_k<<<32768, blk, 0, stream>>>(A, D, 1);
  off_deform(C, D, 2, F, false);

  // layer 3: aligned = deform(fea3, conv(fea3))     F -> C   (D == grouped F)
  regroup_k<<<32768, blk, 0, stream>>>(F, D, 0);
  off_deform(F, D, 3, C, true);

  // recon conv: aligned -> im (8,3,HW)   [VALU fp32, Cout=3]
  conv3x3_k<64, 8, 4, false, false, 0><<<dim3(4, 4, 8), blk, 0, stream>>>(
      C, rcw, rcb, nullptr, im, nullptr, nullptr, 3, 1, 0, 0);

  // assemble outputs
  assemble_k<<<42880, blk, 0, stream>>>(x, im, A, F, out);
}

// Round 11
// 1688.828 us; speedup vs baseline: 1.4254x; 1.0064x over previous
//
#include <hip/hip_runtime.h>

#define HH 128
#define WW 128
#define HWX (HH*WW)

using f32x4 = __attribute__((ext_vector_type(4))) float;
using f16x8 = __attribute__((ext_vector_type(8))) _Float16;

__device__ __forceinline__ unsigned short f16bits(_Float16 h) {
  union { _Float16 f; unsigned short u; } v; v.f = h; return v.u;
}
__device__ __forceinline__ _Float16 f16val(unsigned short u) {
  union { unsigned short u; _Float16 f; } v; v.u = u; return v.f;
}

// chunk swizzle: position pos (64B row of 32 f16), chunk q (16B of 8 f16)
__device__ __forceinline__ int swz(int pos, int q) {
  return pos * 32 + (((q + pos + (pos >> 2)) & 3) << 3);
}

// ---------------------------------------------------------------------------
// Weight prep: OIHW fp32 -> [layer][kpos][O][I] split-fp16 (hi + lo arenas)
// ---------------------------------------------------------------------------
__global__ __launch_bounds__(256) void wprep_k(
    const float* __restrict__ src, unsigned short* __restrict__ dhi,
    unsigned short* __restrict__ dlo, int O, int I, int L)
{
  int idx = blockIdx.x * 256 + threadIdx.x;
  int tot = L * O * I * 9;
  if (idx >= tot) return;
  int per = O * I * 9;
  int layer = idx / per;
  int r = idx - layer * per;
  int o = r / (I * 9);
  int r2 = r - o * (I * 9);
  int i = r2 / 9, k = r2 - i * 9;
  float v = src[idx];
  _Float16 h = (_Float16)v;
  _Float16 l = (_Float16)(v - (float)h);
  long di = (long)layer * per + ((long)k * O + o) * I + i;
  dhi[di] = f16bits(h);
  dlo[di] = f16bits(l);
}

// ---------------------------------------------------------------------------
// Deform weight prep: [L][O=64][I=64][9] fp32 -> [L][k2][o][r=I] split-fp16
// ---------------------------------------------------------------------------
__global__ __launch_bounds__(256) void dwprep_k(
    const float* __restrict__ src, unsigned short* __restrict__ dhi,
    unsigned short* __restrict__ dlo)
{
  int idx = blockIdx.x * 256 + threadIdx.x;      // 4*36864 = 147456
  if (idx >= 147456) return;
  int l = idx / 36864;
  int rem = idx - l * 36864;
  int o = rem / 576;
  int rem2 = rem - o * 576;
  int r = rem2 / 9, k2 = rem2 - r * 9;
  float v = src[idx];
  _Float16 h = (_Float16)v;
  _Float16 lo = (_Float16)(v - (float)h);
  long di = (((long)l * 9 + k2) * 64 + o) * 64 + r;
  dhi[di] = f16bits(h);
  dlo[di] = f16bits(lo);
}

// ---------------------------------------------------------------------------
// Split-fp16 MFMA implicit-GEMM 3x3 SAME conv. Block 256 thr = 4 waves.
// Structure = R8/R10 (session best): single-buffered weight slab in LDS
// + T14 (next slab prefetched to regs during MFMAs, written after a
// read-complete barrier). R9 falsified the no-LDS variant (-36%); R7
// falsified barrier-count; R10 grouped staging for offset convs (-73us).
// SIN: 0 = planar fp32, 1 = pre-split hi/lo arenas (zero conversion VALU),
//      2 = grouped fp32 [img][g][HW][8] (coalesced, bit-identical to 0).
// SOUT: 0 = fp32 only, 1 = split-only, 2 = dual fp32 + split.
// ADDSPLIT (v13): residual-add reads hi+lo from the split output arenas
// (in-place, per-thread read-then-write of same address) instead of the
// 64KB-per-lane strided fp32 planar read — lets res chain drop the fp32
// copy entirely for i<4 (saves ~165MB + strided-read amplification).
// Precision: hi+lo reconstruct ~2^-22 rel (R6 precedent passed).
// ---------------------------------------------------------------------------
template<int CBLK, int NFRAG, bool RELU, bool ADD, bool CRMODE, int SIN, int SOUT,
         bool ADDSPLIT>
__global__ __launch_bounds__(256, 3) void conv_mfma_k(
    const float* __restrict__ in, const unsigned short* __restrict__ inlo,
    const unsigned short* __restrict__ whi, const unsigned short* __restrict__ wlo,
    const float* __restrict__ bias, const float* __restrict__ res,
    float* __restrict__ out, unsigned short* __restrict__ outh,
    unsigned short* __restrict__ outl,
    int Cout, int nslice, int img_in0, int img_out0)
{
  constexpr int CIN = CBLK * 32;
  constexpr int OCB = NFRAG * 16;
  constexpr int SLAB = OCB * 32;               // ushorts per half
  __shared__ __align__(16) unsigned short s_in[2 * 10880];   // 10x34 halo hi|lo
  __shared__ __align__(16) unsigned short s_w[2 * SLAB];     // single buf hi|lo

  const int tid = threadIdx.x;
  const int lane = tid & 63;
  const int wv = tid >> 6;
  const int m16 = lane & 15, q = lane >> 4;
  const int iz = blockIdx.z / nslice, slice = blockIdx.z % nslice;
  const int oc_blk0 = slice * OCB;
  const int x0 = blockIdx.x * 32, y0 = blockIdx.y * 8;

  f32x4 acc[4][NFRAG];
#pragma unroll
  for (int mt = 0; mt < 4; ++mt)
#pragma unroll
    for (int nt = 0; nt < NFRAG; ++nt)
#pragma unroll
      for (int i = 0; i < 4; ++i) acc[mt][nt][i] = 0.f;

  int bb = 0, nn = 0;
  const float* inb = in;
  const unsigned short* inb_h = (const unsigned short*)in;
  const unsigned short* inb_l = inlo;
  if (CRMODE) {
    int j = img_in0 + iz;
    bb = j >> 2;
    int ns = j & 3;
    nn = ns < 2 ? ns : ns + 1;
  } else {
    if (SIN == 1) {
      inb_h += (long)(img_in0 + iz) * CIN * HWX;
      inb_l += (long)(img_in0 + iz) * CIN * HWX;
    } else {
      inb = in + (long)(img_in0 + iz) * CIN * HWX;   // planar or grouped base
    }
  }

  for (int cb = 0; cb < CBLK; ++cb) {
    const int c0 = cb * 32;
    if (cb > 0) __syncthreads();   // protect s_in/s_w overwrite from prev cb
    // ---- stage input tile ----
    for (int t = tid; t < 1360; t += 256) {
      int qq = t / 340, pos = t - qq * 340;
      int iy = pos / 34, ix = pos - iy * 34;
      int gy = y0 + iy - 1, gx = x0 + ix - 1;
      bool inr = (gy >= 0 && gy < HH && gx >= 0 && gx < WW);
      if (SIN == 1) {
        uint4 hv = make_uint4(0u, 0u, 0u, 0u), lv = make_uint4(0u, 0u, 0u, 0u);
        if (inr) {
          long a;
          if (CRMODE) {
            int ch = c0 + qq * 8;
            int simg = (ch < 64) ? (bb * 5 + 2) : (bb * 5 + nn);
            a = ((long)(simg * 8 + ((ch & 63) >> 3)) * HWX + gy * WW + gx) * 8;
            hv = *(const uint4*)((const unsigned short*)in + a);
            lv = *(const uint4*)(inlo + a);
          } else {
            a = (long)(c0 + qq * 8) * HWX + (long)(gy * WW + gx) * 8;
            hv = *(const uint4*)(inb_h + a);
            lv = *(const uint4*)(inb_l + a);
          }
        }
        *(uint4*)(s_in + swz(pos, qq)) = hv;
        *(uint4*)(s_in + 10880 + swz(pos, qq)) = lv;
      } else {
        float vals[8];
        if (SIN == 2) {
          if (inr) {
            long a = (long)((c0 >> 3) + qq) * HWX * 8 + (long)(gy * WW + gx) * 8;
            float4 f0 = ((const float4*)(inb + a))[0];
            float4 f1 = ((const float4*)(inb + a))[1];
            vals[0] = f0.x; vals[1] = f0.y; vals[2] = f0.z; vals[3] = f0.w;
            vals[4] = f1.x; vals[5] = f1.y; vals[6] = f1.z; vals[7] = f1.w;
          } else {
#pragma unroll
            for (int j = 0; j < 8; ++j) vals[j] = 0.f;
          }
        } else {
          const float* src;
          if (CRMODE) {
            int ch = c0 + qq * 8;
            int simg = (ch < 64) ? (bb * 5 + 2) : (bb * 5 + nn);
            src = in + ((long)simg * 64 + (ch & 63)) * HWX + gy * WW + gx;
          } else {
            src = inb + (long)(c0 + qq * 8) * HWX + gy * WW + gx;
          }
#pragma unroll
          for (int j = 0; j < 8; ++j)
            vals[j] = inr ? src[(long)j * HWX] : 0.f;
        }
        unsigned hi4[4], lo4[4];
#pragma unroll
        for (int j2 = 0; j2 < 4; ++j2) {
          unsigned short hs[2], ls[2];
#pragma unroll
          for (int j = 0; j < 2; ++j) {
            float v = vals[j2 * 2 + j];
            _Float16 h = (_Float16)v;
            _Float16 l = (_Float16)(v - (float)h);
            hs[j] = f16bits(h); ls[j] = f16bits(l);
          }
          hi4[j2] = (unsigned)hs[0] | ((unsigned)hs[1] << 16);
          lo4[j2] = (unsigned)ls[0] | ((unsigned)ls[1] << 16);
        }
        *(uint4*)(s_in + swz(pos, qq)) = make_uint4(hi4[0], hi4[1], hi4[2], hi4[3]);
        *(uint4*)(s_in + 10880 + swz(pos, qq)) =
            make_uint4(lo4[0], lo4[1], lo4[2], lo4[3]);
      }
    }
    // ---- stage kp=0 weight slab ----
    for (int t = tid; t < OCB * 4; t += 256) {
      int qq = t & 3, ocl = t >> 2;
      long so = ((long)0 * Cout + oc_blk0 + ocl) * CIN + c0 + qq * 8;
      *(uint4*)(s_w + swz(ocl, qq)) = *(const uint4*)(whi + so);
      *(uint4*)(s_w + SLAB + swz(ocl, qq)) = *(const uint4*)(wlo + so);
    }
    __syncthreads();

#pragma unroll
    for (int kp = 0; kp < 9; ++kp) {
      // T14: issue next-slab global loads now (regs); write after read-barrier.
      uint4 sth, stl;
      int sd = -1;
      if (kp < 8 && tid < OCB * 4) {
        int qq = tid & 3, ocl = tid >> 2;
        long so = ((long)(kp + 1) * Cout + oc_blk0 + ocl) * CIN + c0 + qq * 8;
        sth = *(const uint4*)(whi + so);
        stl = *(const uint4*)(wlo + so);
        sd = swz(ocl, qq);
      }
      const int dy = kp / 3, dx = kp - dy * 3;
      f16x8 bhi[NFRAG], blo[NFRAG];
#pragma unroll
      for (int nt = 0; nt < NFRAG; ++nt) {
        int pw = nt * 16 + m16;
        bhi[nt] = *(const f16x8*)(s_w + swz(pw, q));
        blo[nt] = *(const f16x8*)(s_w + SLAB + swz(pw, q));
      }
#pragma unroll
      for (int mt = 0; mt < 4; ++mt) {
        int r = 2 * wv + (mt >> 1), h = mt & 1;
        int pos = (r + dy) * 34 + h * 16 + m16 + dx;
        f16x8 ahi = *(const f16x8*)(s_in + swz(pos, q));
        f16x8 alo = *(const f16x8*)(s_in + 10880 + swz(pos, q));
#pragma unroll
        for (int nt = 0; nt < NFRAG; ++nt) {
          acc[mt][nt] = __builtin_amdgcn_mfma_f32_16x16x32_f16(
              ahi, blo[nt], acc[mt][nt], 0, 0, 0);
          acc[mt][nt] = __builtin_amdgcn_mfma_f32_16x16x32_f16(
              alo, bhi[nt], acc[mt][nt], 0, 0, 0);
          acc[mt][nt] = __builtin_amdgcn_mfma_f32_16x16x32_f16(
              ahi, bhi[nt], acc[mt][nt], 0, 0, 0);
        }
      }
      if (kp < 8) {
        __syncthreads();           // all waves done reading s_w for this kp
        if (sd >= 0) {
          *(uint4*)(s_w + sd) = sth;
          *(uint4*)(s_w + SLAB + sd) = stl;
        }
        __syncthreads();           // slab ready for kp+1
      }
    }
  }

  const int img_o = img_out0 + iz;
#pragma unroll
  for (int mt = 0; mt < 4; ++mt) {
    int r = 2 * wv + (mt >> 1), h = mt & 1;
    int y = y0 + r;
    int xb = x0 + h * 16 + q * 4;
#pragma unroll
    for (int nt = 0; nt < NFRAG; ++nt) {
      int oc = oc_blk0 + nt * 16 + m16;
      if (oc < Cout) {
        float bsv = bias[oc];
        long base = ((long)img_o * Cout + oc) * HWX + (long)y * WW + xb;
        long gbase = 0;
        if (SOUT || ADDSPLIT)
          gbase = (long)img_o * Cout * HWX + (long)(oc >> 3) * HWX * 8 +
                  ((long)y * WW + xb) * 8 + (oc & 7);
#pragma unroll
        for (int i = 0; i < 4; ++i) {
          float v = acc[mt][nt][i] + bsv;
          if (RELU) v = fmaxf(v, 0.f);
          if (ADD) {
            if (ADDSPLIT) {
              long gi = gbase + (long)i * 8;
              v += (float)f16val(outh[gi]) + (float)f16val(outl[gi]);
            } else {
              v += res[base + i];
            }
          }
          if (SOUT) {
            _Float16 hh = (_Float16)v;
            outh[gbase + (long)i * 8] = f16bits(hh);
            outl[gbase + (long)i * 8] = f16bits((_Float16)(v - (float)hh));
          }
          if (SOUT != 1) out[base + i] = v;
        }
      }
    }
  }
}

// ---------------------------------------------------------------------------
// Fallback VALU conv (conv_first CIN=3 and recon Cout=3).
// SOUT: 0 = fp32 only, 1 = split-only, 2 = dual fp32 + split.
// ---------------------------------------------------------------------------
template<int CIN, int CK, int OCB, bool RELU, bool ADD, int SOUT>
__global__ __launch_bounds__(256) void conv3x3_k(
    const float* __restrict__ in, const float* __restrict__ wgt,
    const float* __restrict__ bias, const float* __restrict__ res,
    float* __restrict__ out, unsigned short* __restrict__ outh,
    unsigned short* __restrict__ outl,
    int Cout, int nslice, int img_in0, int img_out0)
{
  __shared__ __align__(16) float s_in[CK][34][34];
  __shared__ __align__(16) float s_w[CK * 9 * OCB];

  const int tid = threadIdx.x;
  const int tx = tid & 31;
  const int ty = tid >> 5;
  const int iz = blockIdx.z / nslice;
  const int slice = blockIdx.z % nslice;
  const int oc0 = slice * OCB;
  const int x0 = blockIdx.x * 32;
  const int y0 = blockIdx.y * 32;

  float acc[4][OCB];
#pragma unroll
  for (int r = 0; r < 4; ++r)
#pragma unroll
    for (int o = 0; o < OCB; ++o) acc[r][o] = 0.f;

  const float* inb = in + (long)(img_in0 + iz) * CIN * HWX;

  for (int c0 = 0; c0 < CIN; c0 += CK) {
    __syncthreads();
    for (int idx = tid; idx < CK * 34 * 34; idx += 256) {
      int c = idx / 1156;
      int rem = idx % 1156;
      int iy = rem / 34, ix = rem % 34;
      int gy = y0 + iy - 1, gx = x0 + ix - 1;
      float v = 0.f;
      if (gy >= 0 && gy < HH && gx >= 0 && gx < WW)
        v = inb[(long)(c0 + c) * HWX + gy * WW + gx];
      s_in[c][iy][ix] = v;
    }
    for (int idx = tid; idx < CK * 9 * OCB; idx += 256) {
      int oc = idx % OCB;
      int ck = idx / OCB;
      int c = ck / 9, k = ck % 9;
      int ocg = oc0 + oc;
      float v = 0.f;
      if (ocg < Cout) v = wgt[((long)ocg * CIN + c0 + c) * 9 + k];
      s_w[idx] = v;
    }
    __syncthreads();

    for (int c = 0; c < CK; ++c) {
#pragma unroll
      for (int k = 0; k < 9; ++k) {
        const int ky = k / 3, kx = k % 3;
        float v0 = s_in[c][ty + ky][tx + kx];
        float v1 = s_in[c][ty + 8 + ky][tx + kx];
        float v2 = s_in[c][ty + 16 + ky][tx + kx];
        float v3 = s_in[c][ty + 24 + ky][tx + kx];
        const float4* wp = (const float4*)&s_w[(c * 9 + k) * OCB];
#pragma unroll
        for (int o4 = 0; o4 < OCB / 4; ++o4) {
          float4 w4 = wp[o4];
          acc[0][o4 * 4 + 0] += v0 * w4.x; acc[0][o4 * 4 + 1] += v0 * w4.y;
          acc[0][o4 * 4 + 2] += v0 * w4.z; acc[0][o4 * 4 + 3] += v0 * w4.w;
          acc[1][o4 * 4 + 0] += v1 * w4.x; acc[1][o4 * 4 + 1] += v1 * w4.y;
          acc[1][o4 * 4 + 2] += v1 * w4.z; acc[1][o4 * 4 + 3] += v1 * w4.w;
          acc[2][o4 * 4 + 0] += v2 * w4.x; acc[2][o4 * 4 + 1] += v2 * w4.y;
          acc[2][o4 * 4 + 2] += v2 * w4.z; acc[2][o4 * 4 + 3] += v2 * w4.w;
          acc[3][o4 * 4 + 0] += v3 * w4.x; acc[3][o4 * 4 + 1] += v3 * w4.y;
          acc[3][o4 * 4 + 2] += v3 * w4.z; acc[3][o4 * 4 + 3] += v3 * w4.w;
        }
      }
    }
  }

#pragma unroll
  for (int o = 0; o < OCB; ++o) {
    int ocg = oc0 + o;
    if (ocg < Cout) {
      float b = bias ? bias[ocg] : 0.f;
      long base = ((long)(img_out0 + iz) * Cout + ocg) * HWX;
#pragma unroll
      for (int r = 0; r < 4; ++r) {
        int y = y0 + ty + 8 * r;
        float v = acc[r][o] + b;
        if (RELU) v = fmaxf(v, 0.f);
        long ia = base + (long)y * WW + x0 + tx;
        if (ADD) v += res[ia];
        if (SOUT) {
          long ga = (long)(img_out0 + iz) * Cout * HWX + (long)(ocg >> 3) * HWX * 8 +
                    ((long)y * WW + x0 + tx) * 8 + (ocg & 7);
          _Float16 hh = (_Float16)v;
          outh[ga] = f16bits(hh);
          outl[ga] = f16bits((_Float16)(v - (float)hh));
        }
        if (SOUT != 1) out[ia] = v;
      }
    }
  }
}

// ---------------------------------------------------------------------------
__global__ __launch_bounds__(256) void regroup_k(
    const float* __restrict__ src, float* __restrict__ dst, int supp_mode)
{
  int idx = blockIdx.x * 256 + threadIdx.x;
  int c = idx & 7;
  int p = (idx >> 3) & 16383;
  int g = (idx >> 17) & 7;
  int img = idx >> 20;
  int simg = img;
  if (supp_mode) {
    int b = img >> 2, ns = img & 3;
    simg = b * 5 + (ns < 2 ? ns : ns + 1);
  }
  dst[idx] = src[((simg * 64 + g * 8 + c) * HWX) + p];
}

// ---------------------------------------------------------------------------
// Deform v3 (known-good, 155us). R1-R6 falsified every lever: waves (R1/R2),
// pipeline depth (R3), f16 bytes (R4 precision), split-f16 layout (R6 —
// regressed; equal total bytes). Surviving model: per-CU TA processes ~1
// lane-address/cy; fp32 gather floor = 75.6M addrs = ~123us. At 155us this
// config is ~78% of the precision-constrained floor. Frozen.
// ---------------------------------------------------------------------------
__global__ __launch_bounds__(256) void deform_mfma_k(
    const float* __restrict__ srcg, const float* __restrict__ off,
    const unsigned short* __restrict__ wh, const unsigned short* __restrict__ wl,
    float* __restrict__ out, int img0, int cmask, int cshift)
{
  __shared__ __align__(16) unsigned short s_w[2][2 * 4096];
  const int tid = threadIdx.x;
  const int lane = tid & 63;
  const int wv = tid >> 6;
  const int m16 = lane & 15, q = lane >> 4;
  const int bid = blockIdx.x;
  const int iz = bid & cmask;
  const int tile = bid >> cshift;
  const int img = img0 + iz;
  const int tp0 = tile * 64;
  const int p = tp0 + wv * 16 + m16;
  const float fy = (float)(p >> 7), fx = (float)(p & 127);
  const int rot = 8 * (m16 & 7);

  const float* offb = off + (long)iz * 144 * HWX + p;
  const float* sgq[2];
  sgq[0] = srcg + (long)(img * 8 + q) * HWX * 8;        // s=0: g=q
  sgq[1] = srcg + (long)(img * 8 + 4 + q) * HWX * 8;    // s=1: g=4+q

  float dyr[3], dxr[3];
  float pyr[2], pxr[2];
  float4 cr[2][8];

#define LOAD_OFF(T, SLOT) { \
    const float* ob_ = offb + ((long)(4 * ((T) & 1) + q) * 18 + 2 * ((T) >> 1)) * HWX; \
    dyr[SLOT] = ob_[0]; dxr[SLOT] = ob_[HWX]; }

#define ISSUE(T, SLOT, OS) { \
    const int k2_ = (T) >> 1; \
    float py_ = dyr[OS] + fy + (float)(k2_ / 3 - 1); \
    float px_ = dxr[OS] + fx + (float)(k2_ % 3 - 1); \
    pyr[SLOT] = py_; pxr[SLOT] = px_; \
    float y0f_ = floorf(py_), x0f_ = floorf(px_); \
    int yi0_ = (int)fminf(fmaxf(y0f_, 0.f), 127.f); \
    int yi1_ = (int)fminf(fmaxf(y0f_ + 1.f, 0.f), 127.f); \
    int xi0_ = (int)fminf(fmaxf(x0f_, 0.f), 127.f); \
    int xi1_ = (int)fminf(fmaxf(x0f_ + 1.f, 0.f), 127.f); \
    const float* sg_ = sgq[(T) & 1]; \
    const float4* p00_ = (const float4*)(sg_ + ((long)yi0_ * WW + xi0_) * 8); \
    const float4* p01_ = (const float4*)(sg_ + ((long)yi0_ * WW + xi1_) * 8); \
    const float4* p10_ = (const float4*)(sg_ + ((long)yi1_ * WW + xi0_) * 8); \
    const float4* p11_ = (const float4*)(sg_ + ((long)yi1_ * WW + xi1_) * 8); \
    cr[SLOT][0] = p00_[0]; cr[SLOT][1] = p00_[1]; \
    cr[SLOT][2] = p01_[0]; cr[SLOT][3] = p01_[1]; \
    cr[SLOT][4] = p10_[0]; cr[SLOT][5] = p10_[1]; \
    cr[SLOT][6] = p11_[0]; cr[SLOT][7] = p11_[1]; }

#define STAGE(K2) { \
    const int buf_ = (K2) & 1; \
    for (int t2 = tid; t2 < 512; t2 += 256) { \
      int o_ = t2 >> 3, j_ = t2 & 7; \
      int d_ = o_ * 64 + ((8 * j_ + 8 * (o_ & 7)) & 63); \
      long so_ = ((long)(K2) * 64 + o_) * 64 + 8 * j_; \
      *(uint4*)(s_w[buf_] + d_) = *(const uint4*)(wh + so_); \
      *(uint4*)(s_w[buf_] + 4096 + d_) = *(const uint4*)(wl + so_); \
    } }

#define PROCESS(T, SLOT) { \
    float py_ = pyr[SLOT], px_ = pxr[SLOT]; \
    float y0f_ = floorf(py_), x0f_ = floorf(px_); \
    float wy_ = py_ - y0f_, wx_ = px_ - x0f_; \
    float my0 = (y0f_ >= 0.f && y0f_ <= 127.f) ? 1.f : 0.f; \
    float my1 = (y0f_ >= -1.f && y0f_ <= 126.f) ? 1.f : 0.f; \
    float mx0 = (x0f_ >= 0.f && x0f_ <= 127.f) ? 1.f : 0.f; \
    float mx1 = (x0f_ >= -1.f && x0f_ <= 126.f) ? 1.f : 0.f; \
    float w00 = (1.f - wy_) * (1.f - wx_) * my0 * mx0; \
    float w01 = (1.f - wy_) * wx_ * my0 * mx1; \
    float w10 = wy_ * (1.f - wx_) * my1 * mx0; \
    float w11 = wy_ * wx_ * my1 * mx1; \
    f16x8 ah, al; \
    _Pragma("unroll") \
    for (int j = 0; j < 4; ++j) { \
      float v0 = w00 * ((const float*)&cr[SLOT][0])[j] + w01 * ((const float*)&cr[SLOT][2])[j] \
               + w10 * ((const float*)&cr[SLOT][4])[j] + w11 * ((const float*)&cr[SLOT][6])[j]; \
      float v1 = w00 * ((const float*)&cr[SLOT][1])[j] + w01 * ((const float*)&cr[SLOT][3])[j] \
               + w10 * ((const float*)&cr[SLOT][5])[j] + w11 * ((const float*)&cr[SLOT][7])[j]; \
      _Float16 h0 = (_Float16)v0; ah[j] = h0; al[j] = (_Float16)(v0 - (float)h0); \
      _Float16 h1 = (_Float16)v1; ah[4 + j] = h1; al[4 + j] = (_Float16)(v1 - (float)h1); \
    } \
    const unsigned short* wb_ = s_w[((T) >> 1) & 1]; \
    const int roff_ = (32 * ((T) & 1) + 8 * q + rot) & 63; \
    _Pragma("unroll") \
    for (int nt = 0; nt < 4; ++nt) { \
      int o_ = nt * 16 + m16; \
      f16x8 bh = *(const f16x8*)(wb_ + o_ * 64 + roff_); \
      f16x8 bl = *(const f16x8*)(wb_ + 4096 + o_ * 64 + roff_); \
      acc[nt] = __builtin_amdgcn_mfma_f32_16x16x32_f16(ah, bl, acc[nt], 0, 0, 0); \
      acc[nt] = __builtin_amdgcn_mfma_f32_16x16x32_f16(al, bh, acc[nt], 0, 0, 0); \
      acc[nt] = __builtin_amdgcn_mfma_f32_16x16x32_f16(ah, bh, acc[nt], 0, 0, 0); \
    } }

  f32x4 acc[4];
#pragma unroll
  for (int nt = 0; nt < 4; ++nt)
#pragma unroll
    for (int i = 0; i < 4; ++i) acc[nt][i] = 0.f;

  // prologue: fill offset ring, issue corners for step 0, stage slab 0
  LOAD_OFF(0, 0);
  LOAD_OFF(1, 1);
  ISSUE(0, 0, 0);
  LOAD_OFF(2, 2);
  STAGE(0);
  __syncthreads();

#pragma unroll
  for (int k2 = 0; k2 < 9; ++k2) {
    if (k2 < 8) STAGE(k2 + 1);
#pragma unroll
    for (int s = 0; s < 2; ++s) {
      const int t = 2 * k2 + s;
      if (t < 17) ISSUE(t + 1, (t + 1) & 1, (t + 1) % 3);
      if (t < 15) LOAD_OFF(t + 3, (t + 3) % 3);
      PROCESS(t, t & 1);
    }
    __syncthreads();
  }

#undef LOAD_OFF
#undef ISSUE
#undef STAGE
#undef PROCESS

  const long pb = tp0 + wv * 16 + q * 4;
#pragma unroll
  for (int nt = 0; nt < 4; ++nt) {
    int oc = nt * 16 + m16;
    float4 v;
    v.x = acc[nt][0]; v.y = acc[nt][1]; v.z = acc[nt][2]; v.w = acc[nt][3];
    *(float4*)(out + ((long)img * 64 + oc) * HWX + pb) = v;
  }
}

__global__ __launch_bounds__(256) void assemble_k(
    const float* __restrict__ x, const float* __restrict__ im,
    const float* __restrict__ out0, const float* __restrict__ fea,
    float* __restrict__ out)
{
  int idx = blockIdx.x * 256 + threadIdx.x;
  if (idx < 491520) {
    int within = idx % 49152;
    int n = (idx / 49152) % 5;
    int b = idx / (49152 * 5);
    float v;
    if (n == 2) v = x[(b * 5 + 2) * 49152 + within];
    else {
      int j = b * 4 + (n < 2 ? n : n - 1);
      v = im[j * 49152 + within];
    }
    out[idx] = v;
  } else if (idx < 10977280) {
    int idx2 = idx - 491520;
    int within = idx2 % 1048576;
    int n = (idx2 / 1048576) % 5;
    int b = idx2 / (1048576 * 5);
    float v;
    if (n == 2) v = out0[(b * 5 + 2) * 1048576 + within];
    else {
      int j = b * 4 + (n < 2 ? n : n - 1);
      v = fea[j * 1048576 + within];
    }
    out[idx] = v;
  }
}

// ---------------------------------------------------------------------------
extern "C" void kernel_launch(void* const* d_in, const int* in_sizes, int n_in,
                              void* d_out, int out_size, void* d_ws, size_t ws_size,
                              hipStream_t stream) {
  const float* x   = (const float*)d_in[0];
  const float* cfw = (const float*)d_in[1];
  const float* cfb = (const float*)d_in[2];
  const float* rw1 = (const float*)d_in[3];
  const float* rb1 = (const float*)d_in[4];
  const float* rw2 = (const float*)d_in[5];
  const float* rb2 = (const float*)d_in[6];
  const float* crw = (const float*)d_in[7];
  const float* crb = (const float*)d_in[8];
  const float* ofw = (const float*)d_in[9];
  const float* ofb = (const float*)d_in[10];
  const float* dcw = (const float*)d_in[11];
  const float* rcw = (const float*)d_in[12];
  const float* rcb = (const float*)d_in[13];
  float* out = (float*)d_out;

  // conv weight arenas (hi|lo), then deform weight arenas (hi|lo)
  unsigned short* WH = (unsigned short*)d_ws;
  unsigned short* WL = WH + 774144;
  unsigned short* DH = WH + 1548288;
  unsigned short* DL = DH + 147456;
  const long W_res1 = 0, W_res2 = 184320, W_cr = 368640, W_off = 442368;

  float* A = (float*)d_ws + 921600;                  // (10,64,HW) fp32
  float* C = A + 10485760;                           // fea ping (8,64,HW)
  float* D = C + 8388608;                            // grouped / im
  float* F = D + 8388608;                            // fea3
  float* OFF = F + 8388608;                          // offsets (chunk,144,HW)
  float* im = D;

  // split-f16 grouped arenas:
  //  r-split (res1 out -> res2 in): lives in old r region (C + D-head).
  //  A-split (stream: conv_first/res2 out -> res1/cr in + res2 ADDSPLIT):
  //    lives in F + OFF-head, dead after cr (before OFF layer0 write).
  // v13: the stream is split-ONLY through the res chain (fp32 A written
  // only by res2 i=4 for regroup-supp/assemble). Saves ~165MB + the
  // 64KB-strided planar res reads.
  unsigned short* Rh = (unsigned short*)C;
  unsigned short* Rl = Rh + 10485760;
  unsigned short* Ah = (unsigned short*)F;
  unsigned short* Al = Ah + 10485760;

  const size_t fixedF = 921600UL + 10485760UL + 3UL * 8388608UL;
  int chunk = 8;
  while (chunk > 1 && (fixedF + (size_t)chunk * 2359296UL) * sizeof(float) > ws_size)
    chunk >>= 1;
  int cshift = (chunk == 8) ? 3 : (chunk == 4) ? 2 : (chunk == 2) ? 1 : 0;

  dim3 blk(256);

  // weight prep
  wprep_k<<<720, blk, 0, stream>>>(rw1, WH + W_res1, WL + W_res1, 64, 64, 5);
  wprep_k<<<720, blk, 0, stream>>>(rw2, WH + W_res2, WL + W_res2, 64, 64, 5);
  wprep_k<<<288, blk, 0, stream>>>(crw, WH + W_cr, WL + W_cr, 64, 128, 1);
  wprep_k<<<1296, blk, 0, stream>>>(ofw, WH + W_off, WL + W_off, 144, 64, 4);
  dwprep_k<<<576, blk, 0, stream>>>(dcw, DH, DL);

  // conv_first + ReLU : x -> A-split only   [VALU fp32, CIN=3]
  conv3x3_k<3, 3, 16, true, false, 1><<<dim3(4, 4, 40), blk, 0, stream>>>(
      x, cfw, cfb, nullptr, A, Ah, Al, 64, 4, 0, 0);

  // 5 residual blocks (split-fp16 MFMA; split-only stream; LDS weights + T14)
  for (int i = 0; i < 5; ++i) {
    // res1: A-split -> r-split
    conv_mfma_k<2, 4, true, false, false, 1, 1, false>
        <<<dim3(4, 16, 10), blk, 0, stream>>>(
        (const float*)Ah, Al, WH + W_res1 + (long)i * 36864, WL + W_res1 + (long)i * 36864,
        rb1 + i * 64, nullptr, A, Rh, Rl, 64, 1, 0, 0);
    // res2: r-split -> A-split (+res add from A-split, in-place);
    //       i=4 additionally writes fp32 A for regroup-supp/assemble.
    if (i < 4)
      conv_mfma_k<2, 4, false, true, false, 1, 1, true>
          <<<dim3(4, 16, 10), blk, 0, stream>>>(
          (const float*)Rh, Rl, WH + W_res2 + (long)i * 36864, WL + W_res2 + (long)i * 36864,
          rb2 + i * 64, nullptr, A, Ah, Al, 64, 1, 0, 0);
    else
      conv_mfma_k<2, 4, false, true, false, 1, 2, true>
          <<<dim3(4, 16, 10), blk, 0, stream>>>(
          (const float*)Rh, Rl, WH + W_res2 + (long)i * 36864, WL + W_res2 + (long)i * 36864,
          rb2 + i * 64, nullptr, A, Ah, Al, 64, 1, 0, 0);
  }

  // cr conv, fused concat(ref,supp) from A-split: -> C (fea0, fp32)
  conv_mfma_k<4, 4, false, false, true, 1, 0, false>
      <<<dim3(4, 16, 8), blk, 0, stream>>>(
      (const float*)Ah, Al, WH + W_cr, WL + W_cr, crb, nullptr, C, nullptr, nullptr,
      64, 1, 0, 0);

  // offset conv + deform (frozen), chunked.
  // gin=true: stage offset-conv input from grouped fp32 arena D (coalesced,
  // bit-identical values) instead of 8x 64KB-strided planar loads.
  auto off_deform = [&](const float* fea_in, const float* grouped,
                        int layer, float* outp, bool gin) {
    for (int i0 = 0; i0 < 8; i0 += chunk) {
      if (gin)
        conv_mfma_k<2, 3, false, false, false, 2, 0, false>
            <<<dim3(4, 16, chunk * 3), blk, 0, stream>>>(
                grouped, nullptr, WH + W_off + (long)layer * 82944,
                WL + W_off + (long)layer * 82944, ofb + layer * 144,
                nullptr, OFF, nullptr, nullptr, 144, 3, i0, 0);
      else
        conv_mfma_k<2, 3, false, false, false, 0, 0, false>
            <<<dim3(4, 16, chunk * 3), blk, 0, stream>>>(
                fea_in, nullptr, WH + W_off + (long)layer * 82944,
                WL + W_off + (long)layer * 82944, ofb + layer * 144,
                nullptr, OFF, nullptr, nullptr, 144, 3, i0, 0);
      deform_mfma_k<<<dim3(256 * chunk), blk, 0, stream>>>(
          grouped, OFF, DH + (long)layer * 36864, DL + (long)layer * 36864,
          outp, i0, chunk - 1, cshift);
    }
  };

  // layer 0: fea1 = deform(fea0, conv(fea0))        C -> C   (D == grouped C)
  regroup_k<<<32768, blk, 0, stream>>>(C, D, 0);
  off_deform(C, D, 0, C, true);

  // layer 1: fea2 = deform(fea1, conv(fea1))        C -> C   (D == grouped C)
  regroup_k<<<32768, blk, 0, stream>>>(C, D, 0);
  off_deform(C, D, 1, C, true);

  // layer 2: fea3 = deform(supp, conv(fea2))        (A supp, C) -> F
  //          grouped D == supp-A (fp32 A from res2-i4), off-conv input C planar
  regroup_k<<<32768, blk, 0, stream>>>(A, D, 1);
  off_deform(C, D, 2, F, false);

  // layer 3: aligned = deform(fea3, conv(fea3))     F -> C   (D == grouped F)
  regroup_k<<<32768, blk, 0, stream>>>(F, D, 0);
  off_deform(F, D, 3, C, true);

  // recon conv: aligned -> im (8,3,HW)   [VALU fp32, Cout=3]
  conv3x3_k<64, 8, 4, false, false, 0><<<dim3(4, 4, 8), blk, 0, stream>>>(
      C, rcw, rcb, nullptr, im, nullptr, nullptr, 3, 1, 0, 0);

  // assemble outputs
  assemble_k<<<42880, blk, 0, stream>>>(x, im, A, F, out);
}